// Round 1
// baseline (534.506 us; speedup 1.0000x reference)
//
#include <hip/hip_runtime.h>

typedef __attribute__((ext_vector_type(8))) short short8;
typedef __attribute__((ext_vector_type(4))) float f32x4;

constexpr int B_ = 4, T_ = 2048, D_ = 1024, H_ = 16, DK_ = 64;
constexpr int M_ = B_ * T_;          // 8192 token rows
constexpr float SCALE = 0.125f;      // 1/sqrt(64)

#define DEV __device__ __forceinline__

DEV unsigned short f2bf(float f) {   // f32 -> bf16 RNE
  unsigned int u = __builtin_bit_cast(unsigned int, f);
  u += 0x7FFFu + ((u >> 16) & 1u);
  return (unsigned short)(u >> 16);
}

DEV void gload16(const unsigned short* g, unsigned short* l) {
  __builtin_amdgcn_global_load_lds(
      (const __attribute__((address_space(1))) unsigned int*)g,
      (__attribute__((address_space(3))) unsigned int*)l, 16, 0, 0);
}

// ---------------- f32 -> bf16 conversion ----------------
__global__ __launch_bounds__(256) void cvt_bf16(const float* __restrict__ in,
                                                unsigned short* __restrict__ out,
                                                int n) {
  int i = (blockIdx.x * 256 + threadIdx.x) * 4;
  if (i >= n) return;
  float4 f = *(const float4*)(in + i);
  ushort4 o;
  o.x = f2bf(f.x); o.y = f2bf(f.y); o.z = f2bf(f.z); o.w = f2bf(f.w);
  *(ushort4*)(out + i) = o;
}

// ---------------- GEMM: C[M,N] = A[M,K] * B[N,K]^T (bf16 in, bf16/f32 out) ----
// m97 structure: 128x128 tile, BK=32, 4 waves (2x2), 4x4 16x16x32 frags/wave,
// global_load_lds width-16 staging, double-buffered LDS.
template <int OUTF32>
__global__ __launch_bounds__(256, 2) void gemm_bt(const unsigned short* __restrict__ A,
                                                  const unsigned short* __restrict__ B,
                                                  void* __restrict__ C,
                                                  int M, int N, int K) {
  constexpr int BM = 128, BN = 128, BK = 32;
  __shared__ __align__(16) unsigned short a_sh[2 * BM * BK];
  __shared__ __align__(16) unsigned short b_sh[2 * BN * BK];

  const int tid = threadIdx.x;
  const int lane = tid & 63;
  const int w = tid >> 6;          // wave 0..3
  const int l15 = lane & 15, lg = lane >> 4;
  const int wr = w >> 1, wc = w & 1;

  const int NT = N / BN;
  const int tm = blockIdx.x / NT, tn = blockIdx.x % NT;
  const unsigned short* Ab = A + (size_t)tm * BM * K;
  const unsigned short* Bb = B + (size_t)tn * BN * K;

  f32x4 acc[4][4];
#pragma unroll
  for (int m = 0; m < 4; ++m)
#pragma unroll
    for (int n = 0; n < 4; ++n) acc[m][n] = (f32x4){0.f, 0.f, 0.f, 0.f};

  auto stage = [&](int buf, int kt) {
    int k0 = kt * BK;
#pragma unroll
    for (int rnd = 0; rnd < 2; ++rnd) {
      int c = rnd * 256 + tid;            // 16B chunk id, 0..511
      int row = c >> 2, cc = (c & 3) * 8; // 4 chunks per 32-elem row
      gload16(Ab + (size_t)row * K + k0 + cc,
              a_sh + buf * BM * BK + rnd * 2048 + w * 512);
      gload16(Bb + (size_t)row * K + k0 + cc,
              b_sh + buf * BN * BK + rnd * 2048 + w * 512);
    }
  };

  stage(0, 0);
  int cur = 0;
  const int NK = K / BK;
  for (int kt = 0; kt < NK; ++kt) {
    __syncthreads();                       // drains vmcnt -> buf[cur] ready
    if (kt + 1 < NK) stage(cur ^ 1, kt + 1);
    const unsigned short* ab = a_sh + cur * BM * BK;
    const unsigned short* bb = b_sh + cur * BN * BK;
    short8 af[4], bf8[4];
#pragma unroll
    for (int m = 0; m < 4; ++m)
      af[m] = *(const short8*)(ab + (wr * 64 + m * 16 + l15) * BK + lg * 8);
#pragma unroll
    for (int n = 0; n < 4; ++n)
      bf8[n] = *(const short8*)(bb + (wc * 64 + n * 16 + l15) * BK + lg * 8);
#pragma unroll
    for (int m = 0; m < 4; ++m)
#pragma unroll
      for (int n = 0; n < 4; ++n)
        acc[m][n] = __builtin_amdgcn_mfma_f32_16x16x32_bf16(af[m], bf8[n], acc[m][n], 0, 0, 0);
    cur ^= 1;
  }

  const int row0 = tm * BM + wr * 64 + lg * 4;
  const int col0 = tn * BN + wc * 64 + l15;
#pragma unroll
  for (int m = 0; m < 4; ++m)
#pragma unroll
    for (int n = 0; n < 4; ++n)
#pragma unroll
      for (int r = 0; r < 4; ++r) {
        size_t idx = (size_t)(row0 + m * 16 + r) * N + (col0 + n * 16);
        if (OUTF32)
          ((float*)C)[idx] = acc[m][n][r];
        else
          ((unsigned short*)C)[idx] = f2bf(acc[m][n][r]);
      }
}

// ---------------- causal flash attention ----------------
// block = 4 waves = one 64-row Q tile of one (b,h); wave owns 16 q-rows.
// KV tiles of 32. Q,K row-major in LDS (padded), V transposed in LDS.
__global__ __launch_bounds__(256, 2) void attn(const unsigned short* __restrict__ Q,
                                               const unsigned short* __restrict__ K,
                                               const unsigned short* __restrict__ V,
                                               unsigned short* __restrict__ Y) {
  constexpr int QB = 64, KB = 32;
  __shared__ __align__(16) unsigned short q_lds[QB][72];        // pad: stride 144B
  __shared__ __align__(16) unsigned short k_lds[KB][72];
  __shared__ __align__(16) unsigned short vt_lds[DK_][KB + 8];  // V^T, stride 80B
  __shared__ __align__(16) unsigned short p_lds[4][16][40];     // per-wave P

  const int tid = threadIdx.x;
  const int lane = tid & 63;
  const int w = tid >> 6;
  const int l15 = lane & 15, lg = lane >> 4;

  const int qt = blockIdx.x % (T_ / QB);
  const int bh = blockIdx.x / (T_ / QB);
  const int h = bh % H_;
  const int b = bh / H_;
  const int q0 = qt * QB;

  const unsigned short* Qp = Q + ((size_t)(b * T_ + q0)) * D_ + h * DK_;
  const unsigned short* Kp = K + ((size_t)(b * T_)) * D_ + h * DK_;
  const unsigned short* Vp = V + ((size_t)(b * T_)) * D_ + h * DK_;

  // stage Q tile 64x64
#pragma unroll
  for (int i = 0; i < 2; ++i) {
    int c = i * 256 + tid;
    int r = c >> 3, c8 = (c & 7) * 8;
    *(int4*)(&q_lds[r][c8]) = *(const int4*)(Qp + (size_t)r * D_ + c8);
  }
  __syncthreads();

  short8 qf[2];
#pragma unroll
  for (int kh = 0; kh < 2; ++kh)
    qf[kh] = *(const short8*)(&q_lds[w * 16 + l15][kh * 32 + lg * 8]);

  float m_r[4], l_r[4];
  f32x4 o_acc[4];
#pragma unroll
  for (int r = 0; r < 4; ++r) { m_r[r] = -1e30f; l_r[r] = 0.f; }
#pragma unroll
  for (int t = 0; t < 4; ++t) o_acc[t] = (f32x4){0.f, 0.f, 0.f, 0.f};

  const int qrow = q0 + w * 16 + lg * 4;  // + r

  for (int kv0 = 0; kv0 < q0 + QB; kv0 += KB) {
    __syncthreads();  // previous iteration's LDS reads done
    {   // stage K tile 32x64
      int s = tid >> 3, c8 = (tid & 7) * 8;
      *(int4*)(&k_lds[s][c8]) = *(const int4*)(Kp + (size_t)(kv0 + s) * D_ + c8);
    }
    {   // stage V tile transposed: vt[d][s]
      int s = tid >> 3, d0 = (tid & 7) * 8;
      int4 v = *(const int4*)(Vp + (size_t)(kv0 + s) * D_ + d0);
      unsigned short* vs = (unsigned short*)&v;
#pragma unroll
      for (int j = 0; j < 8; ++j) vt_lds[d0 + j][s] = vs[j];
    }
    __syncthreads();

    // S[16q x 32s] = Q K^T
    f32x4 s_acc[2];
#pragma unroll
    for (int sh = 0; sh < 2; ++sh) {
      s_acc[sh] = (f32x4){0.f, 0.f, 0.f, 0.f};
      short8 kf0 = *(const short8*)(&k_lds[sh * 16 + l15][lg * 8]);
      short8 kf1 = *(const short8*)(&k_lds[sh * 16 + l15][32 + lg * 8]);
      s_acc[sh] = __builtin_amdgcn_mfma_f32_16x16x32_bf16(qf[0], kf0, s_acc[sh], 0, 0, 0);
      s_acc[sh] = __builtin_amdgcn_mfma_f32_16x16x32_bf16(qf[1], kf1, s_acc[sh], 0, 0, 0);
    }

    // online softmax (wave-parallel: 16-lane shfl reduce per q-row)
    float p_v[2][4];
#pragma unroll
    for (int r = 0; r < 4; ++r) {
      int qr = qrow + r;
      float s0 = (kv0 + l15      <= qr) ? s_acc[0][r] * SCALE : -1e30f;
      float s1 = (kv0 + 16 + l15 <= qr) ? s_acc[1][r] * SCALE : -1e30f;
      float rm = fmaxf(s0, s1);
#pragma unroll
      for (int off = 1; off < 16; off <<= 1) rm = fmaxf(rm, __shfl_xor(rm, off));
      float mnew = fmaxf(m_r[r], rm);
      float corr = __expf(m_r[r] - mnew);
      float p0 = __expf(s0 - mnew);
      float p1 = __expf(s1 - mnew);
      float ps = p0 + p1;
#pragma unroll
      for (int off = 1; off < 16; off <<= 1) ps += __shfl_xor(ps, off);
      l_r[r] = l_r[r] * corr + ps;
      m_r[r] = mnew;
#pragma unroll
      for (int t = 0; t < 4; ++t) o_acc[t][r] *= corr;
      p_v[0][r] = p0; p_v[1][r] = p1;
    }

    // P (C-layout) -> LDS -> A-frag layout
#pragma unroll
    for (int sh = 0; sh < 2; ++sh)
#pragma unroll
      for (int r = 0; r < 4; ++r)
        p_lds[w][lg * 4 + r][sh * 16 + l15] = f2bf(p_v[sh][r]);

    short8 pf = *(const short8*)(&p_lds[w][l15][lg * 8]);

    // O += P * V   (V^T fragments: col=d, k=s)
#pragma unroll
    for (int t = 0; t < 4; ++t) {
      short8 vf = *(const short8*)(&vt_lds[t * 16 + l15][lg * 8]);
      o_acc[t] = __builtin_amdgcn_mfma_f32_16x16x32_bf16(pf, vf, o_acc[t], 0, 0, 0);
    }
  }

  // epilogue: Y[b, q, h*64+d] = O / l
  unsigned short* Yp = Y + ((size_t)(b * T_ + q0 + w * 16 + lg * 4)) * D_ + h * DK_;
#pragma unroll
  for (int t = 0; t < 4; ++t)
#pragma unroll
    for (int r = 0; r < 4; ++r)
      Yp[(size_t)r * D_ + t * 16 + l15] = f2bf(o_acc[t][r] / l_r[r]);
}

// ---------------- launch ----------------
extern "C" void kernel_launch(void* const* d_in, const int* in_sizes, int n_in,
                              void* d_out, int out_size, void* d_ws, size_t ws_size,
                              hipStream_t stream) {
  const float* x  = (const float*)d_in[0];
  const float* Wq = (const float*)d_in[1];
  const float* Wk = (const float*)d_in[2];
  const float* Wv = (const float*)d_in[3];
  const float* Wo = (const float*)d_in[4];
  float* out = (float*)d_out;

  const size_t NX = (size_t)M_ * D_;  // 8388608
  const size_t NW = (size_t)D_ * D_;  // 1048576
  const size_t need = (4 * NX + 4 * NW) * sizeof(unsigned short);  // ~75.5 MB
  if (ws_size < need) return;  // fail cleanly (output stays poisoned)

  unsigned short* ws  = (unsigned short*)d_ws;
  unsigned short* xb  = ws;            // bf16 x; reused as Yb after attention
  unsigned short* wqb = xb + NX;
  unsigned short* wkb = wqb + NW;
  unsigned short* wvb = wkb + NW;
  unsigned short* wob = wvb + NW;
  unsigned short* Qb  = wob + NW;
  unsigned short* Kb  = Qb + NX;
  unsigned short* Vb  = Kb + NX;
  unsigned short* Yb  = xb;            // alias: x dead after QKV projections

  cvt_bf16<<<(int)(NX / 1024), 256, 0, stream>>>(x, xb, (int)NX);
  cvt_bf16<<<(int)(NW / 1024), 256, 0, stream>>>(Wq, wqb, (int)NW);
  cvt_bf16<<<(int)(NW / 1024), 256, 0, stream>>>(Wk, wkb, (int)NW);
  cvt_bf16<<<(int)(NW / 1024), 256, 0, stream>>>(Wv, wvb, (int)NW);
  cvt_bf16<<<(int)(NW / 1024), 256, 0, stream>>>(Wo, wob, (int)NW);

  const int gemm_grid = (M_ / 128) * (D_ / 128);  // 512
  gemm_bt<0><<<gemm_grid, 256, 0, stream>>>(xb, wqb, Qb, M_, D_, D_);
  gemm_bt<0><<<gemm_grid, 256, 0, stream>>>(xb, wkb, Kb, M_, D_, D_);
  gemm_bt<0><<<gemm_grid, 256, 0, stream>>>(xb, wvb, Vb, M_, D_, D_);

  attn<<<B_ * H_ * (T_ / 64), 256, 0, stream>>>(Qb, Kb, Vb, Yb);

  gemm_bt<1><<<gemm_grid, 256, 0, stream>>>(Yb, wob, out, M_, D_, D_);
}

// Round 3
// 299.094 us; speedup vs baseline: 1.7871x; 1.7871x over previous
//
#include <hip/hip_runtime.h>

typedef __attribute__((ext_vector_type(8))) short short8;
typedef __attribute__((ext_vector_type(4))) float f32x4;
typedef __attribute__((ext_vector_type(2))) unsigned int u32x2;

constexpr int B_ = 4, T_ = 2048, D_ = 1024, H_ = 16;
constexpr int M_ = B_ * T_;          // 8192 token rows
constexpr float SCL = 0.125f;        // 1/sqrt(64)

#define DEV __device__ __forceinline__

DEV unsigned short f2bf(float f) {   // f32 -> bf16 RNE
  unsigned int u = __builtin_bit_cast(unsigned int, f);
  u += 0x7FFFu + ((u >> 16) & 1u);
  return (unsigned short)(u >> 16);
}

DEV void gload16(const unsigned short* g, unsigned short* l) {
  __builtin_amdgcn_global_load_lds(
      (const __attribute__((address_space(1))) unsigned int*)g,
      (__attribute__((address_space(3))) unsigned int*)l, 16, 0, 0);
}

// ---------------- f32 -> bf16 conversion ----------------
__global__ __launch_bounds__(256) void cvt_bf16(const float* __restrict__ in,
                                                unsigned short* __restrict__ out,
                                                int n) {
  int i = (blockIdx.x * 256 + threadIdx.x) * 4;
  if (i >= n) return;
  float4 f = *(const float4*)(in + i);
  ushort4 o;
  o.x = f2bf(f.x); o.y = f2bf(f.y); o.z = f2bf(f.z); o.w = f2bf(f.w);
  *(ushort4*)(out + i) = o;
}

// ---------------- GEMM: C[M,N] = A[M,K] * B[N,K]^T ----------------
// OUTMODE: 0 = bf16 row-major, 1 = f32 row-major,
//          2 = bf16 transposed-per-head: Vt[(m>>11)*16 + (n>>6)][n&63][m&2047]
template <int OUTMODE>
__global__ __launch_bounds__(256, 2) void gemm_bt(const unsigned short* __restrict__ A,
                                                  const unsigned short* __restrict__ B,
                                                  void* __restrict__ C,
                                                  int M, int N, int K) {
  constexpr int BM = 128, BN = 128, BK = 32;
  __shared__ __align__(16) unsigned short a_sh[2 * BM * BK];
  __shared__ __align__(16) unsigned short b_sh[2 * BN * BK];

  const int tid = threadIdx.x;
  const int lane = tid & 63;
  const int w = tid >> 6;
  const int l15 = lane & 15, lg = lane >> 4;
  const int wr = w >> 1, wc = w & 1;

  const int NT = N / BN;
  const int tm = blockIdx.x / NT, tn = blockIdx.x % NT;
  const unsigned short* Ab = A + (size_t)tm * BM * K;
  const unsigned short* Bb = B + (size_t)tn * BN * K;

  f32x4 acc[4][4];
#pragma unroll
  for (int m = 0; m < 4; ++m)
#pragma unroll
    for (int n = 0; n < 4; ++n) acc[m][n] = (f32x4){0.f, 0.f, 0.f, 0.f};

  auto stage = [&](int buf, int kt) {
    int k0 = kt * BK;
#pragma unroll
    for (int rnd = 0; rnd < 2; ++rnd) {
      int c = rnd * 256 + tid;
      int row = c >> 2, cc = (c & 3) * 8;
      gload16(Ab + (size_t)row * K + k0 + cc,
              a_sh + buf * BM * BK + rnd * 2048 + w * 512);
      gload16(Bb + (size_t)row * K + k0 + cc,
              b_sh + buf * BN * BK + rnd * 2048 + w * 512);
    }
  };

  stage(0, 0);
  int cur = 0;
  const int NK = K / BK;
  for (int kt = 0; kt < NK; ++kt) {
    __syncthreads();
    if (kt + 1 < NK) stage(cur ^ 1, kt + 1);
    const unsigned short* ab = a_sh + cur * BM * BK;
    const unsigned short* bb = b_sh + cur * BN * BK;
    short8 af[4], bf8[4];
#pragma unroll
    for (int m = 0; m < 4; ++m)
      af[m] = *(const short8*)(ab + (wr * 64 + m * 16 + l15) * BK + lg * 8);
#pragma unroll
    for (int n = 0; n < 4; ++n)
      bf8[n] = *(const short8*)(bb + (wc * 64 + n * 16 + l15) * BK + lg * 8);
#pragma unroll
    for (int m = 0; m < 4; ++m)
#pragma unroll
      for (int n = 0; n < 4; ++n)
        acc[m][n] = __builtin_amdgcn_mfma_f32_16x16x32_bf16(af[m], bf8[n], acc[m][n], 0, 0, 0);
    cur ^= 1;
  }

  const int row0 = tm * BM + wr * 64 + lg * 4;
  const int col0 = tn * BN + wc * 64 + l15;
#pragma unroll
  for (int m = 0; m < 4; ++m)
#pragma unroll
    for (int n = 0; n < 4; ++n) {
      if (OUTMODE == 2) {
        // V^T-per-head layout: [(b*16+h)][d][s], consecutive r = consecutive s
        int mm = row0 + m * 16;            // r=0 base (r consecutive in s)
        int nn = col0 + n * 16;            // + l15 already in col0
        size_t base = ((size_t)((mm >> 11) * 16 + (nn >> 6))) * 131072 +
                      (size_t)(nn & 63) * 2048 + (mm & 2047);
        ushort4 pk;
        pk.x = f2bf(acc[m][n][0]); pk.y = f2bf(acc[m][n][1]);
        pk.z = f2bf(acc[m][n][2]); pk.w = f2bf(acc[m][n][3]);
        *(ushort4*)((unsigned short*)C + base) = pk;
      } else {
#pragma unroll
        for (int r = 0; r < 4; ++r) {
          size_t idx = (size_t)(row0 + m * 16 + r) * N + (col0 + n * 16);
          if (OUTMODE == 1)
            ((float*)C)[idx] = acc[m][n][r];
          else
            ((unsigned short*)C)[idx] = f2bf(acc[m][n][r]);
        }
      }
    }
}

// ---------------- causal flash attention (swapped-QK, KB=64, QB=128) --------
// 4 waves/block; wave owns 32 q-rows (2 x 16). S^T = mfma(K,Q): q = lane&15 ->
// in-register softmax (trees + 2 shfl_xor). K/Q staged XOR-swizzled via
// global_load_lds; V staged from pre-transposed Vt[bh][d][s] (same pattern as K).
__global__ __launch_bounds__(256, 3) void attn(const unsigned short* __restrict__ Q,
                                               const unsigned short* __restrict__ K,
                                               const unsigned short* __restrict__ Vt,
                                               unsigned short* __restrict__ Y) {
  __shared__ __align__(16) unsigned short k_sh[2][64 * 64];
  __shared__ __align__(16) unsigned short v_sh[2][64 * 64];   // [d][s] rows, swizzled
  __shared__ __align__(16) unsigned short qp_sh[9216];  // union: Q tile (8192) then P (4*32*72)

  const int tid = threadIdx.x;
  const int lane = tid & 63;
  const int w = tid >> 6;
  const int l15 = lane & 15, lg = lane >> 4;

  const int bid = blockIdx.x;
  const int qt_blk = 15 - (bid & 15);          // heavy tiles first
  const int bh = bid >> 4;
  const int h = bh & 15;
  const int b = bh >> 4;
  const int q0 = qt_blk * 128;
  const int qq0 = q0 + 32 * w;                 // this wave's first q-row

  const unsigned short* Qp = Q + ((size_t)(b * T_ + q0)) * D_ + h * 64;
  const unsigned short* Kp = K + ((size_t)(b * T_)) * D_ + h * 64;
  const unsigned short* Vtp = Vt + (size_t)bh * 131072;   // [64 d][2048 s]

  // ---- staging helpers (all global_load_lds, width 16) ----
  auto stK = [&](int buf, int kv0) {
#pragma unroll
    for (int j = 0; j < 2; ++j) {
      int c = j * 256 + tid;
      int row = c >> 3;
      gload16(Kp + (size_t)(kv0 + row) * D_ + 8 * ((c & 7) ^ (row & 7)),
              &k_sh[buf][(j * 256 + w * 64) * 8]);
    }
  };
  auto stV = [&](int buf, int kv0) {
#pragma unroll
    for (int j = 0; j < 2; ++j) {
      int c = j * 256 + tid;
      int d = c >> 3;
      gload16(Vtp + (size_t)d * 2048 + kv0 + 8 * ((c & 7) ^ (d & 7)),
              &v_sh[buf][(j * 256 + w * 64) * 8]);
    }
  };

  // prologue: Q tile (128x64, swizzled) + first K/V tiles
#pragma unroll
  for (int j = 0; j < 4; ++j) {
    int c = j * 256 + tid;
    int row = c >> 3;
    gload16(Qp + (size_t)row * D_ + 8 * ((c & 7) ^ (row & 7)),
            qp_sh + (j * 256 + w * 64) * 8);
  }
  stK(0, 0);
  stV(0, 0);
  __syncthreads();

  // Q fragments to registers (B-frag: row = q, k-contig)
  short8 qf[2][2];
#pragma unroll
  for (int qt = 0; qt < 2; ++qt)
#pragma unroll
    for (int kk = 0; kk < 2; ++kk) {
      int row = 32 * w + 16 * qt + l15;
      int off = (64 * kk + 16 * lg) ^ ((row & 7) << 4);
      qf[qt][kk] = *(const short8*)((const char*)qp_sh + row * 128 + off);
    }
  __syncthreads();  // protect Q region before P overwrites it

  unsigned short* p_w = qp_sh + w * 2304;  // per-wave P: [32 q][72]

  const float NEGINF = -__builtin_inff();
  float ml[2] = {NEGINF, NEGINF};
  float ll[2] = {0.f, 0.f};
  f32x4 o[2][4];
#pragma unroll
  for (int qt = 0; qt < 2; ++qt)
#pragma unroll
    for (int t = 0; t < 4; ++t) o[qt][t] = (f32x4){0.f, 0.f, 0.f, 0.f};

  const int NI = 2 * qt_blk + 2;
  int cur = 0;
  for (int i = 0; i < NI; ++i) {
    const int kv0 = i * 64;
    if (i + 1 < NI) { stK(cur ^ 1, kv0 + 64); stV(cur ^ 1, kv0 + 64); }

    const bool active = (kv0 <= qq0 + 31);
    if (active) {
      // ---- S^T = K * Q^T  (16 MFMA) ----
      f32x4 sacc[2][4];
#pragma unroll
      for (int qt = 0; qt < 2; ++qt)
#pragma unroll
        for (int t = 0; t < 4; ++t) sacc[qt][t] = (f32x4){0.f, 0.f, 0.f, 0.f};
      const char* kb = (const char*)k_sh[cur];
#pragma unroll
      for (int t = 0; t < 4; ++t) {
        int sr = 16 * t + l15;
        int sw = (sr & 7) << 4;
        short8 kf0 = *(const short8*)(kb + sr * 128 + ((16 * lg) ^ sw));
        short8 kf1 = *(const short8*)(kb + sr * 128 + ((64 + 16 * lg) ^ sw));
#pragma unroll
        for (int qt = 0; qt < 2; ++qt) {
          sacc[qt][t] = __builtin_amdgcn_mfma_f32_16x16x32_bf16(kf0, qf[qt][0], sacc[qt][t], 0, 0, 0);
          sacc[qt][t] = __builtin_amdgcn_mfma_f32_16x16x32_bf16(kf1, qf[qt][1], sacc[qt][t], 0, 0, 0);
        }
      }

      // ---- online softmax per q-tile (in-register) ----
      float corr[2];
#pragma unroll
      for (int qt = 0; qt < 2; ++qt) {
        const int qg = qq0 + 16 * qt + l15;
        const bool nomask = (kv0 + 63) <= (qq0 + 16 * qt);
        float sv[16];
#pragma unroll
        for (int t = 0; t < 4; ++t)
#pragma unroll
          for (int r = 0; r < 4; ++r) {
            int sg = kv0 + 16 * t + 4 * lg + r;
            float v = sacc[qt][t][r];
            sv[4 * t + r] = (nomask || sg <= qg) ? v : NEGINF;
          }
        float a8[8], a4[4], a2[2];
#pragma unroll
        for (int k = 0; k < 8; ++k) a8[k] = fmaxf(sv[k], sv[k + 8]);
#pragma unroll
        for (int k = 0; k < 4; ++k) a4[k] = fmaxf(a8[k], a8[k + 4]);
        a2[0] = fmaxf(a4[0], a4[2]); a2[1] = fmaxf(a4[1], a4[3]);
        float mx = fmaxf(a2[0], a2[1]);
        mx = fmaxf(mx, __shfl_xor(mx, 16));
        mx = fmaxf(mx, __shfl_xor(mx, 32));
        float mnew = fmaxf(ml[qt], mx);
        corr[qt] = __expf((ml[qt] - mnew) * SCL);
        float nms = mnew * SCL;
        float pv[16];
#pragma unroll
        for (int k = 0; k < 16; ++k) pv[k] = __expf(fmaf(sv[k], SCL, -nms));
        float s8[8], s4[4], s2[2];
#pragma unroll
        for (int k = 0; k < 8; ++k) s8[k] = pv[k] + pv[k + 8];
#pragma unroll
        for (int k = 0; k < 4; ++k) s4[k] = s8[k] + s8[k + 4];
        s2[0] = s4[0] + s4[2]; s2[1] = s4[1] + s4[3];
        float ps = s2[0] + s2[1];
        ps += __shfl_xor(ps, 16);
        ps += __shfl_xor(ps, 32);
        ll[qt] = ll[qt] * corr[qt] + ps;
        ml[qt] = mnew;
        // pack P -> LDS (b64 per 4 consecutive s)
#pragma unroll
        for (int t = 0; t < 4; ++t) {
          unsigned lo = (unsigned)f2bf(pv[4 * t]) | ((unsigned)f2bf(pv[4 * t + 1]) << 16);
          unsigned hi = (unsigned)f2bf(pv[4 * t + 2]) | ((unsigned)f2bf(pv[4 * t + 3]) << 16);
          u32x2 pk = {lo, hi};
          *(u32x2*)(void*)(p_w + (16 * qt + l15) * 72 + 16 * t + 4 * lg) = pk;
        }
      }
      asm volatile("" ::: "memory");  // order P stores before P frag loads

      // ---- rescale O ----
#pragma unroll
      for (int qt = 0; qt < 2; ++qt)
#pragma unroll
        for (int r = 0; r < 4; ++r) {
          float cr = __shfl(corr[qt], 4 * lg + r);
#pragma unroll
          for (int t = 0; t < 4; ++t) o[qt][t][r] *= cr;
        }

      // ---- O += P * V  (16 MFMA; V B-frag = swizzled short8 from v_sh[d][s]) ----
      short8 pa[2][2];
#pragma unroll
      for (int qt = 0; qt < 2; ++qt)
#pragma unroll
        for (int kk = 0; kk < 2; ++kk)
          pa[qt][kk] = *(const short8*)(p_w + (16 * qt + l15) * 72 + kk * 32 + 8 * lg);

      const char* vbT = (const char*)v_sh[cur];
#pragma unroll
      for (int t = 0; t < 4; ++t) {
        int dr = 16 * t + l15;
        int sw = (dr & 7) << 4;
        short8 vf0 = *(const short8*)(vbT + dr * 128 + ((16 * lg) ^ sw));
        short8 vf1 = *(const short8*)(vbT + dr * 128 + ((64 + 16 * lg) ^ sw));
#pragma unroll
        for (int qt = 0; qt < 2; ++qt) {
          o[qt][t] = __builtin_amdgcn_mfma_f32_16x16x32_bf16(pa[qt][0], vf0, o[qt][t], 0, 0, 0);
          o[qt][t] = __builtin_amdgcn_mfma_f32_16x16x32_bf16(pa[qt][1], vf1, o[qt][t], 0, 0, 0);
        }
      }
    }
    __syncthreads();
    cur ^= 1;
  }

  // ---- epilogue: Y[b, q, h*64 + d] = O / l ----
#pragma unroll
  for (int qt = 0; qt < 2; ++qt) {
    float linv = 1.0f / ll[qt];
#pragma unroll
    for (int r = 0; r < 4; ++r) {
      float li = __shfl(linv, 4 * lg + r);
      int qg = qq0 + 16 * qt + 4 * lg + r;
      unsigned short* Yp = Y + ((size_t)(b * T_ + qg)) * D_ + h * 64;
#pragma unroll
      for (int t = 0; t < 4; ++t)
        Yp[16 * t + l15] = f2bf(o[qt][t][r] * li);
    }
  }
}

// ---------------- launch ----------------
extern "C" void kernel_launch(void* const* d_in, const int* in_sizes, int n_in,
                              void* d_out, int out_size, void* d_ws, size_t ws_size,
                              hipStream_t stream) {
  const float* x  = (const float*)d_in[0];
  const float* Wq = (const float*)d_in[1];
  const float* Wk = (const float*)d_in[2];
  const float* Wv = (const float*)d_in[3];
  const float* Wo = (const float*)d_in[4];
  float* out = (float*)d_out;

  const size_t NX = (size_t)M_ * D_;
  const size_t NW = (size_t)D_ * D_;
  const size_t need = (4 * NX + 4 * NW) * sizeof(unsigned short);
  if (ws_size < need) return;

  unsigned short* ws  = (unsigned short*)d_ws;
  unsigned short* xb  = ws;
  unsigned short* wqb = xb + NX;
  unsigned short* wkb = wqb + NW;
  unsigned short* wvb = wkb + NW;
  unsigned short* wob = wvb + NW;
  unsigned short* Qb  = wob + NW;
  unsigned short* Kb  = Qb + NX;
  unsigned short* Vtb = Kb + NX;   // V in transposed-per-head layout [bh][64][2048]
  unsigned short* Yb  = xb;        // alias: x dead after QKV projections

  cvt_bf16<<<(int)(NX / 1024), 256, 0, stream>>>(x, xb, (int)NX);
  cvt_bf16<<<(int)(NW / 1024), 256, 0, stream>>>(Wq, wqb, (int)NW);
  cvt_bf16<<<(int)(NW / 1024), 256, 0, stream>>>(Wk, wkb, (int)NW);
  cvt_bf16<<<(int)(NW / 1024), 256, 0, stream>>>(Wv, wvb, (int)NW);
  cvt_bf16<<<(int)(NW / 1024), 256, 0, stream>>>(Wo, wob, (int)NW);

  const int gemm_grid = (M_ / 128) * (D_ / 128);  // 512
  gemm_bt<0><<<gemm_grid, 256, 0, stream>>>(xb, wqb, Qb, M_, D_, D_);
  gemm_bt<0><<<gemm_grid, 256, 0, stream>>>(xb, wkb, Kb, M_, D_, D_);
  gemm_bt<2><<<gemm_grid, 256, 0, stream>>>(xb, wvb, Vtb, M_, D_, D_);

  attn<<<B_ * H_ * (T_ / 128), 256, 0, stream>>>(Qb, Kb, Vtb, Yb);

  gemm_bt<1><<<gemm_grid, 256, 0, stream>>>(Yb, wob, out, M_, D_, D_);
}

// Round 7
// 202.215 us; speedup vs baseline: 2.6433x; 1.4791x over previous
//
#include <hip/hip_runtime.h>

typedef __attribute__((ext_vector_type(8))) short short8;
typedef __attribute__((ext_vector_type(4))) float f32x4;
typedef __attribute__((ext_vector_type(2))) unsigned int u32x2;

constexpr int B_ = 4, T_ = 2048, D_ = 1024, H_ = 16;
constexpr int M_ = B_ * T_;          // 8192 token rows
constexpr float SCL = 0.125f;        // 1/sqrt(64)
constexpr float SCL2 = 0.1803368801111f;  // SCL * log2(e)

#if __has_builtin(__builtin_amdgcn_exp2f)
#define EXP2F __builtin_amdgcn_exp2f
#else
#define EXP2F exp2f
#endif

#define DEV __device__ __forceinline__

DEV unsigned short f2bf(float f) {   // f32 -> bf16 RNE
  unsigned int u = __builtin_bit_cast(unsigned int, f);
  u += 0x7FFFu + ((u >> 16) & 1u);
  return (unsigned short)(u >> 16);
}

DEV void gload16(const unsigned short* g, unsigned short* l) {
  __builtin_amdgcn_global_load_lds(
      (const __attribute__((address_space(1))) unsigned int*)g,
      (__attribute__((address_space(3))) unsigned int*)l, 16, 0, 0);
}

// ---------------- f32 -> bf16 conversion ----------------
__global__ __launch_bounds__(256) void cvt_bf16(const float* __restrict__ in,
                                                unsigned short* __restrict__ out,
                                                int n) {
  int i = (blockIdx.x * 256 + threadIdx.x) * 4;
  if (i >= n) return;
  float4 f = *(const float4*)(in + i);
  ushort4 o;
  o.x = f2bf(f.x); o.y = f2bf(f.y); o.z = f2bf(f.z); o.w = f2bf(f.w);
  *(ushort4*)(out + i) = o;
}

// 4 weights in one launch (1024 blocks each)
__global__ __launch_bounds__(256) void cvt_w4(const float* __restrict__ w0, const float* __restrict__ w1,
                                              const float* __restrict__ w2, const float* __restrict__ w3,
                                              unsigned short* __restrict__ o0, unsigned short* __restrict__ o1,
                                              unsigned short* __restrict__ o2, unsigned short* __restrict__ o3) {
  int sel = blockIdx.x >> 10;
  const float* in = sel == 0 ? w0 : sel == 1 ? w1 : sel == 2 ? w2 : w3;
  unsigned short* out = sel == 0 ? o0 : sel == 1 ? o1 : sel == 2 ? o2 : o3;
  int i = ((blockIdx.x & 1023) * 256 + threadIdx.x) * 4;
  float4 f = *(const float4*)(in + i);
  ushort4 o;
  o.x = f2bf(f.x); o.y = f2bf(f.y); o.z = f2bf(f.z); o.w = f2bf(f.w);
  *(ushort4*)(out + i) = o;
}

// ---------------- GEMM: C[M,N] = A[M,K] * B[N,K]^T ----------------
// OUTMODE: 0 = bf16 row-major, 1 = f32 row-major,
//          2 = bf16 transposed-per-head: Vt[(m>>11)*16 + (n>>6)][n&63][m&2047]
template <int OUTMODE>
__global__ __launch_bounds__(256, 2) void gemm_bt(const unsigned short* __restrict__ A,
                                                  const unsigned short* __restrict__ B,
                                                  void* __restrict__ C,
                                                  int M, int N, int K) {
  constexpr int BM = 128, BN = 128, BK = 32;
  __shared__ __align__(16) unsigned short a_sh[2 * BM * BK];
  __shared__ __align__(16) unsigned short b_sh[2 * BN * BK];

  const int tid = threadIdx.x;
  const int lane = tid & 63;
  const int w = tid >> 6;
  const int l15 = lane & 15, lg = lane >> 4;
  const int wr = w >> 1, wc = w & 1;

  const int NT = N / BN;
  const int tm = blockIdx.x / NT, tn = blockIdx.x % NT;
  const unsigned short* Ab = A + (size_t)tm * BM * K;
  const unsigned short* Bb = B + (size_t)tn * BN * K;

  f32x4 acc[4][4];
#pragma unroll
  for (int m = 0; m < 4; ++m)
#pragma unroll
    for (int n = 0; n < 4; ++n) acc[m][n] = (f32x4){0.f, 0.f, 0.f, 0.f};

  auto stage = [&](int buf, int kt) {
    int k0 = kt * BK;
#pragma unroll
    for (int rnd = 0; rnd < 2; ++rnd) {
      int c = rnd * 256 + tid;
      int row = c >> 2, cc = (c & 3) * 8;
      gload16(Ab + (size_t)row * K + k0 + cc,
              a_sh + buf * BM * BK + rnd * 2048 + w * 512);
      gload16(Bb + (size_t)row * K + k0 + cc,
              b_sh + buf * BN * BK + rnd * 2048 + w * 512);
    }
  };

  stage(0, 0);
  int cur = 0;
  const int NK = K / BK;
  for (int kt = 0; kt < NK; ++kt) {
    __syncthreads();
    if (kt + 1 < NK) stage(cur ^ 1, kt + 1);
    const unsigned short* ab = a_sh + cur * BM * BK;
    const unsigned short* bb = b_sh + cur * BN * BK;
    short8 af[4], bf8[4];
#pragma unroll
    for (int m = 0; m < 4; ++m)
      af[m] = *(const short8*)(ab + (wr * 64 + m * 16 + l15) * BK + lg * 8);
#pragma unroll
    for (int n = 0; n < 4; ++n)
      bf8[n] = *(const short8*)(bb + (wc * 64 + n * 16 + l15) * BK + lg * 8);
#pragma unroll
    for (int m = 0; m < 4; ++m)
#pragma unroll
      for (int n = 0; n < 4; ++n)
        acc[m][n] = __builtin_amdgcn_mfma_f32_16x16x32_bf16(af[m], bf8[n], acc[m][n], 0, 0, 0);
    cur ^= 1;
  }

  const int row0 = tm * BM + wr * 64 + lg * 4;
  const int col0 = tn * BN + wc * 64 + l15;
#pragma unroll
  for (int m = 0; m < 4; ++m)
#pragma unroll
    for (int n = 0; n < 4; ++n) {
      if (OUTMODE == 2) {
        int mm = row0 + m * 16;
        int nn = col0 + n * 16;
        size_t base = ((size_t)((mm >> 11) * 16 + (nn >> 6))) * 131072 +
                      (size_t)(nn & 63) * 2048 + (mm & 2047);
        ushort4 pk;
        pk.x = f2bf(acc[m][n][0]); pk.y = f2bf(acc[m][n][1]);
        pk.z = f2bf(acc[m][n][2]); pk.w = f2bf(acc[m][n][3]);
        *(ushort4*)((unsigned short*)C + base) = pk;
      } else {
#pragma unroll
        for (int r = 0; r < 4; ++r) {
          size_t idx = (size_t)(row0 + m * 16 + r) * N + (col0 + n * 16);
          if (OUTMODE == 1)
            ((float*)C)[idx] = acc[m][n][r];
          else
            ((unsigned short*)C)[idx] = f2bf(acc[m][n][r]);
        }
      }
    }
}

// ---------------- causal flash attention (swapped-QK, KB=64, QB=128) --------
__global__ __launch_bounds__(256, 3) void attn(const unsigned short* __restrict__ Q,
                                               const unsigned short* __restrict__ K,
                                               const unsigned short* __restrict__ Vt,
                                               unsigned short* __restrict__ Y) {
  __shared__ __align__(16) unsigned short k_sh[2][64 * 64];
  __shared__ __align__(16) unsigned short v_sh[2][64 * 64];   // [d][s], swizzled
  __shared__ __align__(16) unsigned short p_sh[4][32][72];    // per-wave P

  const int tid = threadIdx.x;
  const int lane = tid & 63;
  const int w = tid >> 6;
  const int l15 = lane & 15, lg = lane >> 4;

  const int bid = blockIdx.x;
  const int qt_blk = 15 - (bid >> 6);          // all heavy blocks dispatch first
  const int bh = bid & 63;
  const int h = bh & 15;
  const int b = bh >> 4;
  const int q0 = qt_blk * 128;
  const int qq0 = q0 + 32 * w;                 // this wave's first q-row

  const unsigned short* Qp = Q + ((size_t)(b * T_ + q0)) * D_ + h * 64;
  const unsigned short* Kp = K + ((size_t)(b * T_)) * D_ + h * 64;
  const unsigned short* Vtp = Vt + (size_t)bh * 131072;   // [64 d][2048 s]

  auto stK = [&](int buf, int kv0) {
#pragma unroll
    for (int j = 0; j < 2; ++j) {
      int c = j * 256 + tid;
      int row = c >> 3;
      gload16(Kp + (size_t)(kv0 + row) * D_ + 8 * ((c & 7) ^ (row & 7)),
              &k_sh[buf][(j * 256 + w * 64) * 8]);
    }
  };
  auto stV = [&](int buf, int kv0) {
#pragma unroll
    for (int j = 0; j < 2; ++j) {
      int c = j * 256 + tid;
      int d = c >> 3;
      gload16(Vtp + (size_t)d * 2048 + kv0 + 8 * ((c & 7) ^ (d & 7)),
              &v_sh[buf][(j * 256 + w * 64) * 8]);
    }
  };

  // Q fragments direct global -> registers (B-frag: row = q, k-contig)
  short8 qf[2][2];
#pragma unroll
  for (int qt = 0; qt < 2; ++qt)
#pragma unroll
    for (int kk = 0; kk < 2; ++kk)
      qf[qt][kk] = *(const short8*)(Qp + (size_t)(32 * w + 16 * qt + l15) * D_ + 32 * kk + 8 * lg);

  stK(0, 0);
  stV(0, 0);
  __syncthreads();

  unsigned short* p_w = &p_sh[w][0][0];

  const float NEGINF = -__builtin_inff();
  float ml[2] = {NEGINF, NEGINF};
  float ll[2] = {0.f, 0.f};
  f32x4 o[2][4];
#pragma unroll
  for (int qt = 0; qt < 2; ++qt)
#pragma unroll
    for (int t = 0; t < 4; ++t) o[qt][t] = (f32x4){0.f, 0.f, 0.f, 0.f};

  const int NI = 2 * qt_blk + 2;
  int cur = 0;
  for (int i = 0; i < NI; ++i) {
    const int kv0 = i * 64;
    if (i + 1 < NI) { stK(cur ^ 1, kv0 + 64); stV(cur ^ 1, kv0 + 64); }

    const bool active = (kv0 <= qq0 + 31);
    if (active) {
      // ---- S^T = K * Q^T  (16 MFMA) ----
      f32x4 sacc[2][4];
#pragma unroll
      for (int qt = 0; qt < 2; ++qt)
#pragma unroll
        for (int t = 0; t < 4; ++t) sacc[qt][t] = (f32x4){0.f, 0.f, 0.f, 0.f};
      const char* kb = (const char*)k_sh[cur];
      __builtin_amdgcn_s_setprio(1);
#pragma unroll
      for (int t = 0; t < 4; ++t) {
        int sr = 16 * t + l15;
        int sw = (sr & 7) << 4;
        short8 kf0 = *(const short8*)(kb + sr * 128 + ((16 * lg) ^ sw));
        short8 kf1 = *(const short8*)(kb + sr * 128 + ((64 + 16 * lg) ^ sw));
#pragma unroll
        for (int qt = 0; qt < 2; ++qt) {
          sacc[qt][t] = __builtin_amdgcn_mfma_f32_16x16x32_bf16(kf0, qf[qt][0], sacc[qt][t], 0, 0, 0);
          sacc[qt][t] = __builtin_amdgcn_mfma_f32_16x16x32_bf16(kf1, qf[qt][1], sacc[qt][t], 0, 0, 0);
        }
      }
      __builtin_amdgcn_s_setprio(0);

      // ---- online softmax per q-tile (in-register) ----
      float corr[2];
#pragma unroll
      for (int qt = 0; qt < 2; ++qt) {
        const bool nomask = (kv0 + 63) <= (qq0 + 16 * qt);   // wave-uniform
        float sv[16];
        if (nomask) {
#pragma unroll
          for (int t = 0; t < 4; ++t)
#pragma unroll
            for (int r = 0; r < 4; ++r) sv[4 * t + r] = sacc[qt][t][r];
        } else {
          const int qg = qq0 + 16 * qt + l15;
#pragma unroll
          for (int t = 0; t < 4; ++t)
#pragma unroll
            for (int r = 0; r < 4; ++r) {
              int sg = kv0 + 16 * t + 4 * lg + r;
              sv[4 * t + r] = (sg <= qg) ? sacc[qt][t][r] : NEGINF;
            }
        }
        float a8[8], a4[4], a2[2];
#pragma unroll
        for (int k = 0; k < 8; ++k) a8[k] = fmaxf(sv[k], sv[k + 8]);
#pragma unroll
        for (int k = 0; k < 4; ++k) a4[k] = fmaxf(a8[k], a8[k + 4]);
        a2[0] = fmaxf(a4[0], a4[2]); a2[1] = fmaxf(a4[1], a4[3]);
        float mx = fmaxf(a2[0], a2[1]);
        mx = fmaxf(mx, __shfl_xor(mx, 16));
        mx = fmaxf(mx, __shfl_xor(mx, 32));
        float mnew = fmaxf(ml[qt], mx);
        corr[qt] = EXP2F((ml[qt] - mnew) * SCL2);
        float nms2 = mnew * SCL2;
        float pv[16];
#pragma unroll
        for (int k = 0; k < 16; ++k) pv[k] = EXP2F(fmaf(sv[k], SCL2, -nms2));
        float s8[8], s4[4], s2[2];
#pragma unroll
        for (int k = 0; k < 8; ++k) s8[k] = pv[k] + pv[k + 8];
#pragma unroll
        for (int k = 0; k < 4; ++k) s4[k] = s8[k] + s8[k + 4];
        s2[0] = s4[0] + s4[2]; s2[1] = s4[1] + s4[3];
        float ps = s2[0] + s2[1];
        ps += __shfl_xor(ps, 16);
        ps += __shfl_xor(ps, 32);
        ll[qt] = ll[qt] * corr[qt] + ps;
        ml[qt] = mnew;
        // pack P -> LDS via v_cvt_pk_bf16_f32 (RNE, lo=src0)
#pragma unroll
        for (int t = 0; t < 4; ++t) {
          unsigned lo, hi;
          asm("v_cvt_pk_bf16_f32 %0, %1, %2" : "=v"(lo) : "v"(pv[4 * t]), "v"(pv[4 * t + 1]));
          asm("v_cvt_pk_bf16_f32 %0, %1, %2" : "=v"(hi) : "v"(pv[4 * t + 2]), "v"(pv[4 * t + 3]));
          u32x2 pk = {lo, hi};
          *(u32x2*)(void*)(p_w + (16 * qt + l15) * 72 + 16 * t + 4 * lg) = pk;
        }
      }
      asm volatile("" ::: "memory");  // order P stores before P frag loads

      // ---- rescale O ----
#pragma unroll
      for (int qt = 0; qt < 2; ++qt)
#pragma unroll
        for (int r = 0; r < 4; ++r) {
          float cr = __shfl(corr[qt], 4 * lg + r);
#pragma unroll
          for (int t = 0; t < 4; ++t) o[qt][t][r] *= cr;
        }

      // ---- O += P * V  (16 MFMA) ----
      short8 pa[2][2];
#pragma unroll
      for (int qt = 0; qt < 2; ++qt)
#pragma unroll
        for (int kk = 0; kk < 2; ++kk)
          pa[qt][kk] = *(const short8*)(p_w + (16 * qt + l15) * 72 + kk * 32 + 8 * lg);

      const char* vbT = (const char*)v_sh[cur];
      __builtin_amdgcn_s_setprio(1);
#pragma unroll
      for (int t = 0; t < 4; ++t) {
        int dr = 16 * t + l15;
        int sw = (dr & 7) << 4;
        short8 vf0 = *(const short8*)(vbT + dr * 128 + ((16 * lg) ^ sw));
        short8 vf1 = *(const short8*)(vbT + dr * 128 + ((64 + 16 * lg) ^ sw));
#pragma unroll
        for (int qt = 0; qt < 2; ++qt) {
          o[qt][t] = __builtin_amdgcn_mfma_f32_16x16x32_bf16(pa[qt][0], vf0, o[qt][t], 0, 0, 0);
          o[qt][t] = __builtin_amdgcn_mfma_f32_16x16x32_bf16(pa[qt][1], vf1, o[qt][t], 0, 0, 0);
        }
      }
      __builtin_amdgcn_s_setprio(0);
    }
    __syncthreads();
    cur ^= 1;
  }

  // ---- epilogue: Y[b, q, h*64 + d] = O / l ----
#pragma unroll
  for (int qt = 0; qt < 2; ++qt) {
    float linv = 1.0f / ll[qt];
#pragma unroll
    for (int r = 0; r < 4; ++r) {
      float li = __shfl(linv, 4 * lg + r);
      int qg = qq0 + 16 * qt + 4 * lg + r;
      unsigned short* Yp = Y + ((size_t)(b * T_ + qg)) * D_ + h * 64;
#pragma unroll
      for (int t = 0; t < 4; ++t)
        Yp[16 * t + l15] = f2bf(o[qt][t][r] * li);
    }
  }
}

// ---------------- launch ----------------
extern "C" void kernel_launch(void* const* d_in, const int* in_sizes, int n_in,
                              void* d_out, int out_size, void* d_ws, size_t ws_size,
                              hipStream_t stream) {
  const float* x  = (const float*)d_in[0];
  const float* Wq = (const float*)d_in[1];
  const float* Wk = (const float*)d_in[2];
  const float* Wv = (const float*)d_in[3];
  const float* Wo = (const float*)d_in[4];
  float* out = (float*)d_out;

  const size_t NX = (size_t)M_ * D_;
  const size_t NW = (size_t)D_ * D_;
  const size_t need = (4 * NX + 4 * NW) * sizeof(unsigned short);
  if (ws_size < need) return;

  unsigned short* ws  = (unsigned short*)d_ws;
  unsigned short* xb  = ws;
  unsigned short* wqb = xb + NX;
  unsigned short* wkb = wqb + NW;
  unsigned short* wvb = wkb + NW;
  unsigned short* wob = wvb + NW;
  unsigned short* Qb  = wob + NW;
  unsigned short* Kb  = Qb + NX;
  unsigned short* Vtb = Kb + NX;   // V transposed-per-head [bh][64][2048]
  unsigned short* Yb  = xb;        // alias: x dead after QKV projections

  cvt_bf16<<<(int)(NX / 1024), 256, 0, stream>>>(x, xb, (int)NX);
  cvt_w4<<<4096, 256, 0, stream>>>(Wq, Wk, Wv, Wo, wqb, wkb, wvb, wob);

  const int gemm_grid = (M_ / 128) * (D_ / 128);  // 512
  gemm_bt<0><<<gemm_grid, 256, 0, stream>>>(xb, wqb, Qb, M_, D_, D_);
  gemm_bt<0><<<gemm_grid, 256, 0, stream>>>(xb, wkb, Kb, M_, D_, D_);
  gemm_bt<2><<<gemm_grid, 256, 0, stream>>>(xb, wvb, Vtb, M_, D_, D_);

  attn<<<B_ * H_ * (T_ / 128), 256, 0, stream>>>(Qb, Kb, Vtb, Yb);

  gemm_bt<1><<<gemm_grid, 256, 0, stream>>>(Yb, wob, out, M_, D_, D_);
}

// Round 8
// 200.567 us; speedup vs baseline: 2.6650x; 1.0082x over previous
//
#include <hip/hip_runtime.h>

typedef __attribute__((ext_vector_type(8))) short short8;
typedef __attribute__((ext_vector_type(4))) float f32x4;
typedef __attribute__((ext_vector_type(2))) unsigned int u32x2;

constexpr int B_ = 4, T_ = 2048, D_ = 1024, H_ = 16;
constexpr int M_ = B_ * T_;          // 8192 token rows
constexpr float SCL2 = 0.1803368801111f;  // (1/sqrt(64)) * log2(e)

#if __has_builtin(__builtin_amdgcn_exp2f)
#define EXP2F __builtin_amdgcn_exp2f
#else
#define EXP2F exp2f
#endif

#define DEV __device__ __forceinline__

DEV unsigned short f2bf(float f) {   // f32 -> bf16 RNE
  unsigned int u = __builtin_bit_cast(unsigned int, f);
  u += 0x7FFFu + ((u >> 16) & 1u);
  return (unsigned short)(u >> 16);
}

DEV void gload16(const unsigned short* g, unsigned short* l) {
  __builtin_amdgcn_global_load_lds(
      (const __attribute__((address_space(1))) unsigned int*)g,
      (__attribute__((address_space(3))) unsigned int*)l, 16, 0, 0);
}

// ---------------- f32 -> bf16 conversion ----------------
__global__ __launch_bounds__(256) void cvt_bf16(const float* __restrict__ in,
                                                unsigned short* __restrict__ out,
                                                int n) {
  int i = (blockIdx.x * 256 + threadIdx.x) * 4;
  if (i >= n) return;
  float4 f = *(const float4*)(in + i);
  ushort4 o;
  o.x = f2bf(f.x); o.y = f2bf(f.y); o.z = f2bf(f.z); o.w = f2bf(f.w);
  *(ushort4*)(out + i) = o;
}

// 4 weights in one launch (1024 blocks each)
__global__ __launch_bounds__(256) void cvt_w4(const float* __restrict__ w0, const float* __restrict__ w1,
                                              const float* __restrict__ w2, const float* __restrict__ w3,
                                              unsigned short* __restrict__ o0, unsigned short* __restrict__ o1,
                                              unsigned short* __restrict__ o2, unsigned short* __restrict__ o3) {
  int sel = blockIdx.x >> 10;
  const float* in = sel == 0 ? w0 : sel == 1 ? w1 : sel == 2 ? w2 : w3;
  unsigned short* out = sel == 0 ? o0 : sel == 1 ? o1 : sel == 2 ? o2 : o3;
  int i = ((blockIdx.x & 1023) * 256 + threadIdx.x) * 4;
  float4 f = *(const float4*)(in + i);
  ushort4 o;
  o.x = f2bf(f.x); o.y = f2bf(f.y); o.z = f2bf(f.z); o.w = f2bf(f.w);
  *(ushort4*)(out + i) = o;
}

// ---------------- GEMM: C[M,N] = A[M,K] * B[N,K]^T ----------------
// OUTMODE: 0 = bf16 row-major, 1 = f32 row-major,
//          3 = fused QKV: region by tn (0-7 Q, 8-15 K, 16-23 Vt-per-head)
template <int OUTMODE>
__global__ __launch_bounds__(256, 3) void gemm_bt(const unsigned short* __restrict__ A,
                                                  const unsigned short* __restrict__ B,
                                                  void* __restrict__ C,
                                                  int M, int N, int K) {
  constexpr int BM = 128, BN = 128, BK = 32;
  __shared__ __align__(16) unsigned short a_sh[2 * BM * BK];
  __shared__ __align__(16) unsigned short b_sh[2 * BN * BK];

  const int tid = threadIdx.x;
  const int lane = tid & 63;
  const int w = tid >> 6;
  const int l15 = lane & 15, lg = lane >> 4;
  const int wr = w >> 1, wc = w & 1;

  const int NT = N / BN;
  const int tm = blockIdx.x / NT, tn = blockIdx.x % NT;
  const unsigned short* Ab = A + (size_t)tm * BM * K;
  const unsigned short* Bb = B + (size_t)tn * BN * K;

  f32x4 acc[4][4];
#pragma unroll
  for (int m = 0; m < 4; ++m)
#pragma unroll
    for (int n = 0; n < 4; ++n) acc[m][n] = (f32x4){0.f, 0.f, 0.f, 0.f};

  auto stage = [&](int buf, int kt) {
    int k0 = kt * BK;
#pragma unroll
    for (int rnd = 0; rnd < 2; ++rnd) {
      int c = rnd * 256 + tid;
      int row = c >> 2, cc = (c & 3) * 8;
      gload16(Ab + (size_t)row * K + k0 + cc,
              a_sh + buf * BM * BK + rnd * 2048 + w * 512);
      gload16(Bb + (size_t)row * K + k0 + cc,
              b_sh + buf * BN * BK + rnd * 2048 + w * 512);
    }
  };

  stage(0, 0);
  int cur = 0;
  const int NK = K / BK;
  for (int kt = 0; kt < NK; ++kt) {
    __syncthreads();
    if (kt + 1 < NK) stage(cur ^ 1, kt + 1);
    const unsigned short* ab = a_sh + cur * BM * BK;
    const unsigned short* bb = b_sh + cur * BN * BK;
    short8 af[4], bf8[4];
#pragma unroll
    for (int m = 0; m < 4; ++m)
      af[m] = *(const short8*)(ab + (wr * 64 + m * 16 + l15) * BK + lg * 8);
#pragma unroll
    for (int n = 0; n < 4; ++n)
      bf8[n] = *(const short8*)(bb + (wc * 64 + n * 16 + l15) * BK + lg * 8);
#pragma unroll
    for (int m = 0; m < 4; ++m)
#pragma unroll
      for (int n = 0; n < 4; ++n)
        acc[m][n] = __builtin_amdgcn_mfma_f32_16x16x32_bf16(af[m], bf8[n], acc[m][n], 0, 0, 0);
    cur ^= 1;
  }

  const int row0 = tm * BM + wr * 64 + lg * 4;
  const int col0 = tn * BN + wc * 64 + l15;
#pragma unroll
  for (int m = 0; m < 4; ++m)
#pragma unroll
    for (int n = 0; n < 4; ++n) {
      if (OUTMODE == 3) {
        const int region = tn >> 3;               // 0=Q, 1=K, 2=V
        const int nc = col0 - (region << 10) + n * 16;
        const int mm = row0 + m * 16;
        if (region == 2) {
          // Vt-per-head: [(b*16+h)][d][s], r consecutive in s
          size_t base = (size_t)2 * 8388608 +
                        ((size_t)((mm >> 11) * 16 + (nc >> 6))) * 131072 +
                        (size_t)(nc & 63) * 2048 + (mm & 2047);
          ushort4 pk;
          pk.x = f2bf(acc[m][n][0]); pk.y = f2bf(acc[m][n][1]);
          pk.z = f2bf(acc[m][n][2]); pk.w = f2bf(acc[m][n][3]);
          *(ushort4*)((unsigned short*)C + base) = pk;
        } else {
          unsigned short* dst = (unsigned short*)C + (size_t)region * 8388608;
#pragma unroll
          for (int r = 0; r < 4; ++r)
            dst[(size_t)(mm + r) * 1024 + nc] = f2bf(acc[m][n][r]);
        }
      } else {
#pragma unroll
        for (int r = 0; r < 4; ++r) {
          size_t idx = (size_t)(row0 + m * 16 + r) * N + (col0 + n * 16);
          if (OUTMODE == 1)
            ((float*)C)[idx] = acc[m][n][r];
          else
            ((unsigned short*)C)[idx] = f2bf(acc[m][n][r]);
        }
      }
    }
}

// ---------------- causal flash attention (swapped-QK, KB=64, QB=128) --------
__global__ __launch_bounds__(256, 4) void attn(const unsigned short* __restrict__ Q,
                                               const unsigned short* __restrict__ K,
                                               const unsigned short* __restrict__ Vt,
                                               unsigned short* __restrict__ Y) {
  __shared__ __align__(16) unsigned short k_sh[2][64 * 64];
  __shared__ __align__(16) unsigned short v_sh[2][64 * 64];   // [d][s], swizzled
  __shared__ __align__(16) unsigned short p_sh[4][16 * 64];   // per-wave P, per-qt reuse

  const int tid = threadIdx.x;
  const int lane = tid & 63;
  const int w = tid >> 6;
  const int l15 = lane & 15, lg = lane >> 4;

  const int bid = blockIdx.x;
  const int qt_blk = 15 - (bid >> 6);          // all heavy blocks dispatch first
  const int bh = bid & 63;
  const int h = bh & 15;
  const int b = bh >> 4;
  const int q0 = qt_blk * 128;
  const int qq0 = q0 + 32 * w;                 // this wave's first q-row

  const unsigned short* Qp = Q + ((size_t)(b * T_ + q0)) * D_ + h * 64;
  const unsigned short* Kp = K + ((size_t)(b * T_)) * D_ + h * 64;
  const unsigned short* Vtp = Vt + (size_t)bh * 131072;   // [64 d][2048 s]

  auto stK = [&](int buf, int kv0) {
#pragma unroll
    for (int j = 0; j < 2; ++j) {
      int c = j * 256 + tid;
      int row = c >> 3;
      gload16(Kp + (size_t)(kv0 + row) * D_ + 8 * ((c & 7) ^ (row & 7)),
              &k_sh[buf][(j * 256 + w * 64) * 8]);
    }
  };
  auto stV = [&](int buf, int kv0) {
#pragma unroll
    for (int j = 0; j < 2; ++j) {
      int c = j * 256 + tid;
      int d = c >> 3;
      gload16(Vtp + (size_t)d * 2048 + kv0 + 8 * ((c & 7) ^ (d & 7)),
              &v_sh[buf][(j * 256 + w * 64) * 8]);
    }
  };

  // Q fragments direct global -> registers (B-frag: row = q, k-contig)
  short8 qf[2][2];
#pragma unroll
  for (int qt = 0; qt < 2; ++qt)
#pragma unroll
    for (int kk = 0; kk < 2; ++kk)
      qf[qt][kk] = *(const short8*)(Qp + (size_t)(32 * w + 16 * qt + l15) * D_ + 32 * kk + 8 * lg);

  stK(0, 0);
  stV(0, 0);
  __syncthreads();

  char* p_w = (char*)&p_sh[w][0];

  const float NEGINF = -__builtin_inff();
  float ml[2] = {NEGINF, NEGINF};
  float ll[2] = {0.f, 0.f};
  f32x4 o[2][4];
#pragma unroll
  for (int qt = 0; qt < 2; ++qt)
#pragma unroll
    for (int t = 0; t < 4; ++t) o[qt][t] = (f32x4){0.f, 0.f, 0.f, 0.f};

  const int NI = 2 * qt_blk + 2;
  int cur = 0;
  for (int i = 0; i < NI; ++i) {
    const int kv0 = i * 64;
    if (i + 1 < NI) { stK(cur ^ 1, kv0 + 64); stV(cur ^ 1, kv0 + 64); }

    const bool active = (kv0 <= qq0 + 31);
    if (active) {
      // ---- S^T = K * Q^T  (16 MFMA) ----
      f32x4 sacc[2][4];
#pragma unroll
      for (int qt = 0; qt < 2; ++qt)
#pragma unroll
        for (int t = 0; t < 4; ++t) sacc[qt][t] = (f32x4){0.f, 0.f, 0.f, 0.f};
      const char* kb = (const char*)k_sh[cur];
      __builtin_amdgcn_s_setprio(1);
#pragma unroll
      for (int t = 0; t < 4; ++t) {
        int sr = 16 * t + l15;
        int sw = (sr & 7) << 4;
        short8 kf0 = *(const short8*)(kb + sr * 128 + ((16 * lg) ^ sw));
        short8 kf1 = *(const short8*)(kb + sr * 128 + ((64 + 16 * lg) ^ sw));
#pragma unroll
        for (int qt = 0; qt < 2; ++qt) {
          sacc[qt][t] = __builtin_amdgcn_mfma_f32_16x16x32_bf16(kf0, qf[qt][0], sacc[qt][t], 0, 0, 0);
          sacc[qt][t] = __builtin_amdgcn_mfma_f32_16x16x32_bf16(kf1, qf[qt][1], sacc[qt][t], 0, 0, 0);
        }
      }
      __builtin_amdgcn_s_setprio(0);

      // ---- online softmax per q-tile (in-register, defer-max) ----
      short8 pa[2][2];
#pragma unroll
      for (int qt = 0; qt < 2; ++qt) {
        const bool nomask = (kv0 + 63) <= (qq0 + 16 * qt);   // wave-uniform
        float sv[16];
        if (nomask) {
#pragma unroll
          for (int t = 0; t < 4; ++t)
#pragma unroll
            for (int r = 0; r < 4; ++r) sv[4 * t + r] = sacc[qt][t][r];
        } else {
          const int qg = qq0 + 16 * qt + l15;
#pragma unroll
          for (int t = 0; t < 4; ++t)
#pragma unroll
            for (int r = 0; r < 4; ++r) {
              int sg = kv0 + 16 * t + 4 * lg + r;
              sv[4 * t + r] = (sg <= qg) ? sacc[qt][t][r] : NEGINF;
            }
        }
        float a8[8], a4[4], a2[2];
#pragma unroll
        for (int k = 0; k < 8; ++k) a8[k] = fmaxf(sv[k], sv[k + 8]);
#pragma unroll
        for (int k = 0; k < 4; ++k) a4[k] = fmaxf(a8[k], a8[k + 4]);
        a2[0] = fmaxf(a4[0], a4[2]); a2[1] = fmaxf(a4[1], a4[3]);
        float mx = fmaxf(a2[0], a2[1]);
        mx = fmaxf(mx, __shfl_xor(mx, 16));
        mx = fmaxf(mx, __shfl_xor(mx, 32));
        // T13 defer-max: skip rescale when max growth small (P <= e^1.45)
        const bool defer = (__all(mx <= ml[qt] + 8.0f) != 0);
        float mnew = defer ? ml[qt] : fmaxf(ml[qt], mx);
        float corr = defer ? 1.0f : EXP2F((ml[qt] - mnew) * SCL2);
        float nms2 = mnew * SCL2;
        float pv[16];
#pragma unroll
        for (int k = 0; k < 16; ++k) pv[k] = EXP2F(fmaf(sv[k], SCL2, -nms2));
        float s8[8], s4[4], s2[2];
#pragma unroll
        for (int k = 0; k < 8; ++k) s8[k] = pv[k] + pv[k + 8];
#pragma unroll
        for (int k = 0; k < 4; ++k) s4[k] = s8[k] + s8[k + 4];
        s2[0] = s4[0] + s4[2]; s2[1] = s4[1] + s4[3];
        float ps = s2[0] + s2[1];
        ps += __shfl_xor(ps, 16);
        ps += __shfl_xor(ps, 32);
        ll[qt] = ll[qt] * corr + ps;
        ml[qt] = mnew;
        if (!defer) {   // rescale O (wave-uniform branch)
#pragma unroll
          for (int r = 0; r < 4; ++r) {
            float cr = __shfl(corr, 4 * lg + r);
#pragma unroll
            for (int t = 0; t < 4; ++t) o[qt][t][r] *= cr;
          }
        }
        // pack P -> per-wave LDS (row l15, XOR-swizzled), then read A-frags
        asm volatile("" ::: "memory");
#pragma unroll
        for (int t = 0; t < 4; ++t) {
          unsigned lo, hi;
          asm("v_cvt_pk_bf16_f32 %0, %1, %2" : "=v"(lo) : "v"(pv[4 * t]), "v"(pv[4 * t + 1]));
          asm("v_cvt_pk_bf16_f32 %0, %1, %2" : "=v"(hi) : "v"(pv[4 * t + 2]), "v"(pv[4 * t + 3]));
          u32x2 pk = {lo, hi};
          int byte = l15 * 128 + (((16 * t + 4 * lg) * 2) ^ ((l15 & 7) << 4));
          *(u32x2*)(p_w + byte) = pk;
        }
        asm volatile("" ::: "memory");
#pragma unroll
        for (int kk = 0; kk < 2; ++kk) {
          int byte = l15 * 128 + ((kk * 64 + 16 * lg) ^ ((l15 & 7) << 4));
          pa[qt][kk] = *(const short8*)(p_w + byte);
        }
      }

      // ---- O += P * V  (16 MFMA) ----
      const char* vbT = (const char*)v_sh[cur];
      __builtin_amdgcn_s_setprio(1);
#pragma unroll
      for (int t = 0; t < 4; ++t) {
        int dr = 16 * t + l15;
        int sw = (dr & 7) << 4;
        short8 vf0 = *(const short8*)(vbT + dr * 128 + ((16 * lg) ^ sw));
        short8 vf1 = *(const short8*)(vbT + dr * 128 + ((64 + 16 * lg) ^ sw));
#pragma unroll
        for (int qt = 0; qt < 2; ++qt) {
          o[qt][t] = __builtin_amdgcn_mfma_f32_16x16x32_bf16(pa[qt][0], vf0, o[qt][t], 0, 0, 0);
          o[qt][t] = __builtin_amdgcn_mfma_f32_16x16x32_bf16(pa[qt][1], vf1, o[qt][t], 0, 0, 0);
        }
      }
      __builtin_amdgcn_s_setprio(0);
    }
    __syncthreads();
    cur ^= 1;
  }

  // ---- epilogue: Y[b, q, h*64 + d] = O / l ----
#pragma unroll
  for (int qt = 0; qt < 2; ++qt) {
    float linv = 1.0f / ll[qt];
#pragma unroll
    for (int r = 0; r < 4; ++r) {
      float li = __shfl(linv, 4 * lg + r);
      int qg = qq0 + 16 * qt + 4 * lg + r;
      unsigned short* Yp = Y + ((size_t)(b * T_ + qg)) * D_ + h * 64;
#pragma unroll
      for (int t = 0; t < 4; ++t)
        Yp[16 * t + l15] = f2bf(o[qt][t][r] * li);
    }
  }
}

// ---------------- launch ----------------
extern "C" void kernel_launch(void* const* d_in, const int* in_sizes, int n_in,
                              void* d_out, int out_size, void* d_ws, size_t ws_size,
                              hipStream_t stream) {
  const float* x  = (const float*)d_in[0];
  const float* Wq = (const float*)d_in[1];
  const float* Wk = (const float*)d_in[2];
  const float* Wv = (const float*)d_in[3];
  const float* Wo = (const float*)d_in[4];
  float* out = (float*)d_out;

  const size_t NX = (size_t)M_ * D_;
  const size_t NW = (size_t)D_ * D_;
  const size_t need = (4 * NX + 4 * NW) * sizeof(unsigned short);
  if (ws_size < need) return;

  unsigned short* ws  = (unsigned short*)d_ws;
  unsigned short* xb  = ws;
  unsigned short* wqb = xb + NX;   // wqb/wkb/wvb contiguous = stacked QKV weight
  unsigned short* wkb = wqb + NW;
  unsigned short* wvb = wkb + NW;
  unsigned short* wob = wvb + NW;
  unsigned short* Qb  = wob + NW;  // Qb/Kb/Vtb contiguous = fused-QKV output
  unsigned short* Yb  = xb;        // alias: x dead after QKV projections

  cvt_bf16<<<(int)(NX / 1024), 256, 0, stream>>>(x, xb, (int)NX);
  cvt_w4<<<4096, 256, 0, stream>>>(Wq, Wk, Wv, Wo, wqb, wkb, wvb, wob);

  // fused QKV projection: C[8192, 3072] = x @ [Wq;Wk;Wv]^T
  gemm_bt<3><<<(M_ / 128) * (3072 / 128), 256, 0, stream>>>(xb, wqb, Qb, M_, 3072, D_);

  attn<<<B_ * H_ * (T_ / 128), 256, 0, stream>>>(Qb, Qb + NX, Qb + 2 * NX, Yb);

  gemm_bt<1><<<(M_ / 128) * (D_ / 128), 256, 0, stream>>>(Yb, wob, out, M_, D_, D_);
}

// Round 9
// 180.645 us; speedup vs baseline: 2.9589x; 1.1103x over previous
//
#include <hip/hip_runtime.h>

typedef __attribute__((ext_vector_type(8))) short short8;
typedef __attribute__((ext_vector_type(4))) float f32x4;
typedef __attribute__((ext_vector_type(2))) unsigned int u32x2;

constexpr int B_ = 4, T_ = 2048, D_ = 1024, H_ = 16;
constexpr int M_ = B_ * T_;          // 8192 token rows
constexpr float SCL2 = 0.1803368801111f;  // (1/sqrt(64)) * log2(e)

#if __has_builtin(__builtin_amdgcn_exp2f)
#define EXP2F __builtin_amdgcn_exp2f
#else
#define EXP2F exp2f
#endif

#define DEV __device__ __forceinline__

DEV unsigned short f2bf(float f) {   // f32 -> bf16 RNE
  unsigned int u = __builtin_bit_cast(unsigned int, f);
  u += 0x7FFFu + ((u >> 16) & 1u);
  return (unsigned short)(u >> 16);
}

DEV void gload16(const unsigned short* g, unsigned short* l) {
  __builtin_amdgcn_global_load_lds(
      (const __attribute__((address_space(1))) unsigned int*)g,
      (__attribute__((address_space(3))) unsigned int*)l, 16, 0, 0);
}

// ---------------- f32 -> bf16 conversion ----------------
__global__ __launch_bounds__(256) void cvt_bf16(const float* __restrict__ in,
                                                unsigned short* __restrict__ out,
                                                int n) {
  int i = (blockIdx.x * 256 + threadIdx.x) * 4;
  if (i >= n) return;
  float4 f = *(const float4*)(in + i);
  ushort4 o;
  o.x = f2bf(f.x); o.y = f2bf(f.y); o.z = f2bf(f.z); o.w = f2bf(f.w);
  *(ushort4*)(out + i) = o;
}

// 4 weights in one launch (1024 blocks each)
__global__ __launch_bounds__(256) void cvt_w4(const float* __restrict__ w0, const float* __restrict__ w1,
                                              const float* __restrict__ w2, const float* __restrict__ w3,
                                              unsigned short* __restrict__ o0, unsigned short* __restrict__ o1,
                                              unsigned short* __restrict__ o2, unsigned short* __restrict__ o3) {
  int sel = blockIdx.x >> 10;
  const float* in = sel == 0 ? w0 : sel == 1 ? w1 : sel == 2 ? w2 : w3;
  unsigned short* out = sel == 0 ? o0 : sel == 1 ? o1 : sel == 2 ? o2 : o3;
  int i = ((blockIdx.x & 1023) * 256 + threadIdx.x) * 4;
  float4 f = *(const float4*)(in + i);
  ushort4 o;
  o.x = f2bf(f.x); o.y = f2bf(f.y); o.z = f2bf(f.z); o.w = f2bf(f.w);
  *(ushort4*)(out + i) = o;
}

// ---------------- GEMM: C[M,N] = A[M,K] * B[N,K]^T ----------------
// OUTMODE: 0 = bf16 row-major, 1 = f32 row-major,
//          3 = fused QKV: region by tn (0-7 Q, 8-15 K, 16-23 Vt-per-head)
template <int OUTMODE>
__global__ __launch_bounds__(256, 3) void gemm_bt(const unsigned short* __restrict__ A,
                                                  const unsigned short* __restrict__ B,
                                                  void* __restrict__ C,
                                                  int M, int N, int K) {
  constexpr int BM = 128, BN = 128, BK = 32;
  __shared__ __align__(16) unsigned short a_sh[2 * BM * BK];
  __shared__ __align__(16) unsigned short b_sh[2 * BN * BK];

  const int tid = threadIdx.x;
  const int lane = tid & 63;
  const int w = tid >> 6;
  const int l15 = lane & 15, lg = lane >> 4;
  const int wr = w >> 1, wc = w & 1;

  const int NT = N / BN;
  const int tm = blockIdx.x / NT, tn = blockIdx.x % NT;
  const unsigned short* Ab = A + (size_t)tm * BM * K;
  const unsigned short* Bb = B + (size_t)tn * BN * K;

  f32x4 acc[4][4];
#pragma unroll
  for (int m = 0; m < 4; ++m)
#pragma unroll
    for (int n = 0; n < 4; ++n) acc[m][n] = (f32x4){0.f, 0.f, 0.f, 0.f};

  auto stage = [&](int buf, int kt) {
    int k0 = kt * BK;
#pragma unroll
    for (int rnd = 0; rnd < 2; ++rnd) {
      int c = rnd * 256 + tid;
      int row = c >> 2, cc = (c & 3) * 8;
      gload16(Ab + (size_t)row * K + k0 + cc,
              a_sh + buf * BM * BK + rnd * 2048 + w * 512);
      gload16(Bb + (size_t)row * K + k0 + cc,
              b_sh + buf * BN * BK + rnd * 2048 + w * 512);
    }
  };

  stage(0, 0);
  int cur = 0;
  const int NK = K / BK;
  for (int kt = 0; kt < NK; ++kt) {
    __syncthreads();
    if (kt + 1 < NK) stage(cur ^ 1, kt + 1);
    const unsigned short* ab = a_sh + cur * BM * BK;
    const unsigned short* bb = b_sh + cur * BN * BK;
    short8 af[4], bf8[4];
#pragma unroll
    for (int m = 0; m < 4; ++m)
      af[m] = *(const short8*)(ab + (wr * 64 + m * 16 + l15) * BK + lg * 8);
#pragma unroll
    for (int n = 0; n < 4; ++n)
      bf8[n] = *(const short8*)(bb + (wc * 64 + n * 16 + l15) * BK + lg * 8);
#pragma unroll
    for (int m = 0; m < 4; ++m)
#pragma unroll
      for (int n = 0; n < 4; ++n)
        acc[m][n] = __builtin_amdgcn_mfma_f32_16x16x32_bf16(af[m], bf8[n], acc[m][n], 0, 0, 0);
    cur ^= 1;
  }

  const int row0 = tm * BM + wr * 64 + lg * 4;
  const int col0 = tn * BN + wc * 64 + l15;
#pragma unroll
  for (int m = 0; m < 4; ++m)
#pragma unroll
    for (int n = 0; n < 4; ++n) {
      if (OUTMODE == 3) {
        const int region = tn >> 3;               // 0=Q, 1=K, 2=V
        const int nc = col0 - (region << 10) + n * 16;
        const int mm = row0 + m * 16;
        if (region == 2) {
          // Vt-per-head: [(b*16+h)][d][s], r consecutive in s
          size_t base = (size_t)2 * 8388608 +
                        ((size_t)((mm >> 11) * 16 + (nc >> 6))) * 131072 +
                        (size_t)(nc & 63) * 2048 + (mm & 2047);
          ushort4 pk;
          pk.x = f2bf(acc[m][n][0]); pk.y = f2bf(acc[m][n][1]);
          pk.z = f2bf(acc[m][n][2]); pk.w = f2bf(acc[m][n][3]);
          *(ushort4*)((unsigned short*)C + base) = pk;
        } else {
          unsigned short* dst = (unsigned short*)C + (size_t)region * 8388608;
#pragma unroll
          for (int r = 0; r < 4; ++r)
            dst[(size_t)(mm + r) * 1024 + nc] = f2bf(acc[m][n][r]);
        }
      } else {
#pragma unroll
        for (int r = 0; r < 4; ++r) {
          size_t idx = (size_t)(row0 + m * 16 + r) * N + (col0 + n * 16);
          if (OUTMODE == 1)
            ((float*)C)[idx] = acc[m][n][r];
          else
            ((unsigned short*)C)[idx] = f2bf(acc[m][n][r]);
        }
      }
    }
}

// ---------------- causal flash attention (swapped-QK, KB=64, QB=128) --------
// Round-7 structure (78 us): LDS 51200, (256,3), padded P, single fence.
__global__ __launch_bounds__(256, 3) void attn(const unsigned short* __restrict__ Q,
                                               const unsigned short* __restrict__ K,
                                               const unsigned short* __restrict__ Vt,
                                               unsigned short* __restrict__ Y) {
  __shared__ __align__(16) unsigned short k_sh[2][64 * 64];
  __shared__ __align__(16) unsigned short v_sh[2][64 * 64];   // [d][s], swizzled
  __shared__ __align__(16) unsigned short p_sh[4][32][72];    // per-wave P

  const int tid = threadIdx.x;
  const int lane = tid & 63;
  const int w = tid >> 6;
  const int l15 = lane & 15, lg = lane >> 4;

  const int bid = blockIdx.x;
  const int qt_blk = 15 - (bid >> 6);          // all heavy blocks dispatch first
  const int bh = bid & 63;
  const int h = bh & 15;
  const int b = bh >> 4;
  const int q0 = qt_blk * 128;
  const int qq0 = q0 + 32 * w;                 // this wave's first q-row

  const unsigned short* Qp = Q + ((size_t)(b * T_ + q0)) * D_ + h * 64;
  const unsigned short* Kp = K + ((size_t)(b * T_)) * D_ + h * 64;
  const unsigned short* Vtp = Vt + (size_t)bh * 131072;   // [64 d][2048 s]

  auto stK = [&](int buf, int kv0) {
#pragma unroll
    for (int j = 0; j < 2; ++j) {
      int c = j * 256 + tid;
      int row = c >> 3;
      gload16(Kp + (size_t)(kv0 + row) * D_ + 8 * ((c & 7) ^ (row & 7)),
              &k_sh[buf][(j * 256 + w * 64) * 8]);
    }
  };
  auto stV = [&](int buf, int kv0) {
#pragma unroll
    for (int j = 0; j < 2; ++j) {
      int c = j * 256 + tid;
      int d = c >> 3;
      gload16(Vtp + (size_t)d * 2048 + kv0 + 8 * ((c & 7) ^ (d & 7)),
              &v_sh[buf][(j * 256 + w * 64) * 8]);
    }
  };

  // Q fragments direct global -> registers (B-frag: row = q, k-contig)
  short8 qf[2][2];
#pragma unroll
  for (int qt = 0; qt < 2; ++qt)
#pragma unroll
    for (int kk = 0; kk < 2; ++kk)
      qf[qt][kk] = *(const short8*)(Qp + (size_t)(32 * w + 16 * qt + l15) * D_ + 32 * kk + 8 * lg);

  stK(0, 0);
  stV(0, 0);
  __syncthreads();

  unsigned short* p_w = &p_sh[w][0][0];

  const float NEGINF = -__builtin_inff();
  float ml[2] = {NEGINF, NEGINF};
  float ll[2] = {0.f, 0.f};
  f32x4 o[2][4];
#pragma unroll
  for (int qt = 0; qt < 2; ++qt)
#pragma unroll
    for (int t = 0; t < 4; ++t) o[qt][t] = (f32x4){0.f, 0.f, 0.f, 0.f};

  const int NI = 2 * qt_blk + 2;
  int cur = 0;
  for (int i = 0; i < NI; ++i) {
    const int kv0 = i * 64;
    if (i + 1 < NI) { stK(cur ^ 1, kv0 + 64); stV(cur ^ 1, kv0 + 64); }

    const bool active = (kv0 <= qq0 + 31);
    if (active) {
      // ---- S^T = K * Q^T  (16 MFMA) ----
      f32x4 sacc[2][4];
#pragma unroll
      for (int qt = 0; qt < 2; ++qt)
#pragma unroll
        for (int t = 0; t < 4; ++t) sacc[qt][t] = (f32x4){0.f, 0.f, 0.f, 0.f};
      const char* kb = (const char*)k_sh[cur];
      __builtin_amdgcn_s_setprio(1);
#pragma unroll
      for (int t = 0; t < 4; ++t) {
        int sr = 16 * t + l15;
        int sw = (sr & 7) << 4;
        short8 kf0 = *(const short8*)(kb + sr * 128 + ((16 * lg) ^ sw));
        short8 kf1 = *(const short8*)(kb + sr * 128 + ((64 + 16 * lg) ^ sw));
#pragma unroll
        for (int qt = 0; qt < 2; ++qt) {
          sacc[qt][t] = __builtin_amdgcn_mfma_f32_16x16x32_bf16(kf0, qf[qt][0], sacc[qt][t], 0, 0, 0);
          sacc[qt][t] = __builtin_amdgcn_mfma_f32_16x16x32_bf16(kf1, qf[qt][1], sacc[qt][t], 0, 0, 0);
        }
      }
      __builtin_amdgcn_s_setprio(0);

      // ---- online softmax per q-tile (in-register) ----
      float corr[2];
#pragma unroll
      for (int qt = 0; qt < 2; ++qt) {
        const bool nomask = (kv0 + 63) <= (qq0 + 16 * qt);   // wave-uniform
        float sv[16];
        if (nomask) {
#pragma unroll
          for (int t = 0; t < 4; ++t)
#pragma unroll
            for (int r = 0; r < 4; ++r) sv[4 * t + r] = sacc[qt][t][r];
        } else {
          const int qg = qq0 + 16 * qt + l15;
#pragma unroll
          for (int t = 0; t < 4; ++t)
#pragma unroll
            for (int r = 0; r < 4; ++r) {
              int sg = kv0 + 16 * t + 4 * lg + r;
              sv[4 * t + r] = (sg <= qg) ? sacc[qt][t][r] : NEGINF;
            }
        }
        float a8[8], a4[4], a2[2];
#pragma unroll
        for (int k = 0; k < 8; ++k) a8[k] = fmaxf(sv[k], sv[k + 8]);
#pragma unroll
        for (int k = 0; k < 4; ++k) a4[k] = fmaxf(a8[k], a8[k + 4]);
        a2[0] = fmaxf(a4[0], a4[2]); a2[1] = fmaxf(a4[1], a4[3]);
        float mx = fmaxf(a2[0], a2[1]);
        mx = fmaxf(mx, __shfl_xor(mx, 16));
        mx = fmaxf(mx, __shfl_xor(mx, 32));
        float mnew = fmaxf(ml[qt], mx);
        corr[qt] = EXP2F((ml[qt] - mnew) * SCL2);
        float nms2 = mnew * SCL2;
        float pv[16];
#pragma unroll
        for (int k = 0; k < 16; ++k) pv[k] = EXP2F(fmaf(sv[k], SCL2, -nms2));
        float s8[8], s4[4], s2[2];
#pragma unroll
        for (int k = 0; k < 8; ++k) s8[k] = pv[k] + pv[k + 8];
#pragma unroll
        for (int k = 0; k < 4; ++k) s4[k] = s8[k] + s8[k + 4];
        s2[0] = s4[0] + s4[2]; s2[1] = s4[1] + s4[3];
        float ps = s2[0] + s2[1];
        ps += __shfl_xor(ps, 16);
        ps += __shfl_xor(ps, 32);
        ll[qt] = ll[qt] * corr[qt] + ps;
        ml[qt] = mnew;
        // pack P -> LDS via v_cvt_pk_bf16_f32 (RNE, lo=src0)
#pragma unroll
        for (int t = 0; t < 4; ++t) {
          unsigned lo, hi;
          asm("v_cvt_pk_bf16_f32 %0, %1, %2" : "=v"(lo) : "v"(pv[4 * t]), "v"(pv[4 * t + 1]));
          asm("v_cvt_pk_bf16_f32 %0, %1, %2" : "=v"(hi) : "v"(pv[4 * t + 2]), "v"(pv[4 * t + 3]));
          u32x2 pk = {lo, hi};
          *(u32x2*)(void*)(p_w + (16 * qt + l15) * 72 + 16 * t + 4 * lg) = pk;
        }
      }
      asm volatile("" ::: "memory");  // order P stores before P frag loads

      // ---- rescale O ----
#pragma unroll
      for (int qt = 0; qt < 2; ++qt)
#pragma unroll
        for (int r = 0; r < 4; ++r) {
          float cr = __shfl(corr[qt], 4 * lg + r);
#pragma unroll
          for (int t = 0; t < 4; ++t) o[qt][t][r] *= cr;
        }

      // ---- O += P * V  (16 MFMA) ----
      short8 pa[2][2];
#pragma unroll
      for (int qt = 0; qt < 2; ++qt)
#pragma unroll
        for (int kk = 0; kk < 2; ++kk)
          pa[qt][kk] = *(const short8*)(p_w + (16 * qt + l15) * 72 + kk * 32 + 8 * lg);

      const char* vbT = (const char*)v_sh[cur];
      __builtin_amdgcn_s_setprio(1);
#pragma unroll
      for (int t = 0; t < 4; ++t) {
        int dr = 16 * t + l15;
        int sw = (dr & 7) << 4;
        short8 vf0 = *(const short8*)(vbT + dr * 128 + ((16 * lg) ^ sw));
        short8 vf1 = *(const short8*)(vbT + dr * 128 + ((64 + 16 * lg) ^ sw));
#pragma unroll
        for (int qt = 0; qt < 2; ++qt) {
          o[qt][t] = __builtin_amdgcn_mfma_f32_16x16x32_bf16(pa[qt][0], vf0, o[qt][t], 0, 0, 0);
          o[qt][t] = __builtin_amdgcn_mfma_f32_16x16x32_bf16(pa[qt][1], vf1, o[qt][t], 0, 0, 0);
        }
      }
      __builtin_amdgcn_s_setprio(0);
    }
    __syncthreads();
    cur ^= 1;
  }

  // ---- epilogue: Y[b, q, h*64 + d] = O / l ----
#pragma unroll
  for (int qt = 0; qt < 2; ++qt) {
    float linv = 1.0f / ll[qt];
#pragma unroll
    for (int r = 0; r < 4; ++r) {
      float li = __shfl(linv, 4 * lg + r);
      int qg = qq0 + 16 * qt + 4 * lg + r;
      unsigned short* Yp = Y + ((size_t)(b * T_ + qg)) * D_ + h * 64;
#pragma unroll
      for (int t = 0; t < 4; ++t)
        Yp[16 * t + l15] = f2bf(o[qt][t][r] * li);
    }
  }
}

// ---------------- launch ----------------
extern "C" void kernel_launch(void* const* d_in, const int* in_sizes, int n_in,
                              void* d_out, int out_size, void* d_ws, size_t ws_size,
                              hipStream_t stream) {
  const float* x  = (const float*)d_in[0];
  const float* Wq = (const float*)d_in[1];
  const float* Wk = (const float*)d_in[2];
  const float* Wv = (const float*)d_in[3];
  const float* Wo = (const float*)d_in[4];
  float* out = (float*)d_out;

  const size_t NX = (size_t)M_ * D_;
  const size_t NW = (size_t)D_ * D_;
  const size_t need = (4 * NX + 4 * NW) * sizeof(unsigned short);
  if (ws_size < need) return;

  unsigned short* ws  = (unsigned short*)d_ws;
  unsigned short* xb  = ws;
  unsigned short* wqb = xb + NX;   // wqb/wkb/wvb contiguous = stacked QKV weight
  unsigned short* wkb = wqb + NW;
  unsigned short* wvb = wkb + NW;
  unsigned short* wob = wvb + NW;
  unsigned short* Qb  = wob + NW;  // Qb/Kb/Vtb contiguous = fused-QKV output
  unsigned short* Yb  = xb;        // alias: x dead after QKV projections

  cvt_bf16<<<(int)(NX / 1024), 256, 0, stream>>>(x, xb, (int)NX);
  cvt_w4<<<4096, 256, 0, stream>>>(Wq, Wk, Wv, Wo, wqb, wkb, wvb, wob);

  // fused QKV projection: C[8192, 3072] = x @ [Wq;Wk;Wv]^T
  gemm_bt<3><<<(M_ / 128) * (3072 / 128), 256, 0, stream>>>(xb, wqb, Qb, M_, 3072, D_);

  attn<<<B_ * H_ * (T_ / 128), 256, 0, stream>>>(Qb, Qb + NX, Qb + 2 * NX, Yb);

  gemm_bt<1><<<(M_ / 128) * (D_ / 128), 256, 0, stream>>>(Yb, wob, out, M_, D_, D_);
}

// Round 10
// 175.860 us; speedup vs baseline: 3.0394x; 1.0272x over previous
//
#include <hip/hip_runtime.h>

typedef __attribute__((ext_vector_type(8))) short short8;
typedef __attribute__((ext_vector_type(4))) float f32x4;
typedef __attribute__((ext_vector_type(2))) unsigned int u32x2;

constexpr int B_ = 4, T_ = 2048, D_ = 1024, H_ = 16;
constexpr int M_ = B_ * T_;          // 8192 token rows
constexpr float SCL2 = 0.1803368801111f;  // (1/sqrt(64)) * log2(e)

#if __has_builtin(__builtin_amdgcn_exp2f)
#define EXP2F __builtin_amdgcn_exp2f
#else
#define EXP2F exp2f
#endif

#define DEV __device__ __forceinline__

DEV unsigned short f2bf(float f) {   // f32 -> bf16 RNE
  unsigned int u = __builtin_bit_cast(unsigned int, f);
  u += 0x7FFFu + ((u >> 16) & 1u);
  return (unsigned short)(u >> 16);
}

DEV void gload16(const unsigned short* g, unsigned short* l) {
  __builtin_amdgcn_global_load_lds(
      (const __attribute__((address_space(1))) unsigned int*)g,
      (__attribute__((address_space(3))) unsigned int*)l, 16, 0, 0);
}

// ---------------- f32 -> bf16 conversion ----------------
__global__ __launch_bounds__(256) void cvt_bf16(const float* __restrict__ in,
                                                unsigned short* __restrict__ out,
                                                int n) {
  int i = (blockIdx.x * 256 + threadIdx.x) * 4;
  if (i >= n) return;
  float4 f = *(const float4*)(in + i);
  ushort4 o;
  o.x = f2bf(f.x); o.y = f2bf(f.y); o.z = f2bf(f.z); o.w = f2bf(f.w);
  *(ushort4*)(out + i) = o;
}

// 4 weights in one launch (1024 blocks each)
__global__ __launch_bounds__(256) void cvt_w4(const float* __restrict__ w0, const float* __restrict__ w1,
                                              const float* __restrict__ w2, const float* __restrict__ w3,
                                              unsigned short* __restrict__ o0, unsigned short* __restrict__ o1,
                                              unsigned short* __restrict__ o2, unsigned short* __restrict__ o3) {
  int sel = blockIdx.x >> 10;
  const float* in = sel == 0 ? w0 : sel == 1 ? w1 : sel == 2 ? w2 : w3;
  unsigned short* out = sel == 0 ? o0 : sel == 1 ? o1 : sel == 2 ? o2 : o3;
  int i = ((blockIdx.x & 1023) * 256 + threadIdx.x) * 4;
  float4 f = *(const float4*)(in + i);
  ushort4 o;
  o.x = f2bf(f.x); o.y = f2bf(f.y); o.z = f2bf(f.z); o.w = f2bf(f.w);
  *(ushort4*)(out + i) = o;
}

// ---------------- GEMM: C[M,N] = A[M,K] * B[N,K]^T ----------------
// OUTMODE: 0 = bf16 row-major, 1 = f32 row-major,
//          3 = fused QKV: region by tn (0-7 Q, 8-15 K, 16-23 Vt-per-head)
// T1 XCD swizzle: grid must be a multiple of 8 (1536 and 512 both are).
template <int OUTMODE>
__global__ __launch_bounds__(256, 2) void gemm_bt(const unsigned short* __restrict__ A,
                                                  const unsigned short* __restrict__ B,
                                                  void* __restrict__ C,
                                                  int M, int N, int K) {
  constexpr int BM = 128, BN = 128, BK = 32;
  __shared__ __align__(16) unsigned short a_sh[2 * BM * BK];
  __shared__ __align__(16) unsigned short b_sh[2 * BN * BK];

  const int tid = threadIdx.x;
  const int lane = tid & 63;
  const int w = tid >> 6;
  const int l15 = lane & 15, lg = lane >> 4;
  const int wr = w >> 1, wc = w & 1;

  // XCD-chunked bijective swizzle: each XCD gets a contiguous run of tiles
  const int nwg = gridDim.x;
  const int swz = (blockIdx.x & 7) * (nwg >> 3) + (blockIdx.x >> 3);

  const int NT = N / BN;
  const int tm = swz / NT, tn = swz % NT;
  const unsigned short* Ab = A + (size_t)tm * BM * K;
  const unsigned short* Bb = B + (size_t)tn * BN * K;

  f32x4 acc[4][4];
#pragma unroll
  for (int m = 0; m < 4; ++m)
#pragma unroll
    for (int n = 0; n < 4; ++n) acc[m][n] = (f32x4){0.f, 0.f, 0.f, 0.f};

  auto stage = [&](int buf, int kt) {
    int k0 = kt * BK;
#pragma unroll
    for (int rnd = 0; rnd < 2; ++rnd) {
      int c = rnd * 256 + tid;
      int row = c >> 2, cc = (c & 3) * 8;
      gload16(Ab + (size_t)row * K + k0 + cc,
              a_sh + buf * BM * BK + rnd * 2048 + w * 512);
      gload16(Bb + (size_t)row * K + k0 + cc,
              b_sh + buf * BN * BK + rnd * 2048 + w * 512);
    }
  };

  stage(0, 0);
  int cur = 0;
  const int NK = K / BK;
  for (int kt = 0; kt < NK; ++kt) {
    __syncthreads();
    if (kt + 1 < NK) stage(cur ^ 1, kt + 1);
    const unsigned short* ab = a_sh + cur * BM * BK;
    const unsigned short* bb = b_sh + cur * BN * BK;
    short8 af[4], bf8[4];
#pragma unroll
    for (int m = 0; m < 4; ++m)
      af[m] = *(const short8*)(ab + (wr * 64 + m * 16 + l15) * BK + lg * 8);
#pragma unroll
    for (int n = 0; n < 4; ++n)
      bf8[n] = *(const short8*)(bb + (wc * 64 + n * 16 + l15) * BK + lg * 8);
#pragma unroll
    for (int m = 0; m < 4; ++m)
#pragma unroll
      for (int n = 0; n < 4; ++n)
        acc[m][n] = __builtin_amdgcn_mfma_f32_16x16x32_bf16(af[m], bf8[n], acc[m][n], 0, 0, 0);
    cur ^= 1;
  }

  const int row0 = tm * BM + wr * 64 + lg * 4;
  const int col0 = tn * BN + wc * 64 + l15;
#pragma unroll
  for (int m = 0; m < 4; ++m)
#pragma unroll
    for (int n = 0; n < 4; ++n) {
      if (OUTMODE == 3) {
        const int region = tn >> 3;               // 0=Q, 1=K, 2=V
        const int nc = col0 - (region << 10) + n * 16;
        const int mm = row0 + m * 16;
        if (region == 2) {
          // Vt-per-head: [(b*16+h)][d][s], r consecutive in s
          size_t base = (size_t)2 * 8388608 +
                        ((size_t)((mm >> 11) * 16 + (nc >> 6))) * 131072 +
                        (size_t)(nc & 63) * 2048 + (mm & 2047);
          ushort4 pk;
          pk.x = f2bf(acc[m][n][0]); pk.y = f2bf(acc[m][n][1]);
          pk.z = f2bf(acc[m][n][2]); pk.w = f2bf(acc[m][n][3]);
          *(ushort4*)((unsigned short*)C + base) = pk;
        } else {
          unsigned short* dst = (unsigned short*)C + (size_t)region * 8388608;
#pragma unroll
          for (int r = 0; r < 4; ++r)
            dst[(size_t)(mm + r) * 1024 + nc] = f2bf(acc[m][n][r]);
        }
      } else {
#pragma unroll
        for (int r = 0; r < 4; ++r) {
          size_t idx = (size_t)(row0 + m * 16 + r) * N + (col0 + n * 16);
          if (OUTMODE == 1)
            ((float*)C)[idx] = acc[m][n][r];
          else
            ((unsigned short*)C)[idx] = f2bf(acc[m][n][r]);
        }
      }
    }
}

// ---------------- causal flash attention (swapped-QK, KB=64, QB=128) --------
// Round-7 structure + T13 defer-max (single isolated change).
__global__ __launch_bounds__(256, 3) void attn(const unsigned short* __restrict__ Q,
                                               const unsigned short* __restrict__ K,
                                               const unsigned short* __restrict__ Vt,
                                               unsigned short* __restrict__ Y) {
  __shared__ __align__(16) unsigned short k_sh[2][64 * 64];
  __shared__ __align__(16) unsigned short v_sh[2][64 * 64];   // [d][s], swizzled
  __shared__ __align__(16) unsigned short p_sh[4][32][72];    // per-wave P

  const int tid = threadIdx.x;
  const int lane = tid & 63;
  const int w = tid >> 6;
  const int l15 = lane & 15, lg = lane >> 4;

  const int bid = blockIdx.x;
  const int qt_blk = 15 - (bid >> 6);          // all heavy blocks dispatch first
  const int bh = bid & 63;
  const int h = bh & 15;
  const int b = bh >> 4;
  const int q0 = qt_blk * 128;
  const int qq0 = q0 + 32 * w;                 // this wave's first q-row

  const unsigned short* Qp = Q + ((size_t)(b * T_ + q0)) * D_ + h * 64;
  const unsigned short* Kp = K + ((size_t)(b * T_)) * D_ + h * 64;
  const unsigned short* Vtp = Vt + (size_t)bh * 131072;   // [64 d][2048 s]

  auto stK = [&](int buf, int kv0) {
#pragma unroll
    for (int j = 0; j < 2; ++j) {
      int c = j * 256 + tid;
      int row = c >> 3;
      gload16(Kp + (size_t)(kv0 + row) * D_ + 8 * ((c & 7) ^ (row & 7)),
              &k_sh[buf][(j * 256 + w * 64) * 8]);
    }
  };
  auto stV = [&](int buf, int kv0) {
#pragma unroll
    for (int j = 0; j < 2; ++j) {
      int c = j * 256 + tid;
      int d = c >> 3;
      gload16(Vtp + (size_t)d * 2048 + kv0 + 8 * ((c & 7) ^ (d & 7)),
              &v_sh[buf][(j * 256 + w * 64) * 8]);
    }
  };

  // Q fragments direct global -> registers (B-frag: row = q, k-contig)
  short8 qf[2][2];
#pragma unroll
  for (int qt = 0; qt < 2; ++qt)
#pragma unroll
    for (int kk = 0; kk < 2; ++kk)
      qf[qt][kk] = *(const short8*)(Qp + (size_t)(32 * w + 16 * qt + l15) * D_ + 32 * kk + 8 * lg);

  stK(0, 0);
  stV(0, 0);
  __syncthreads();

  unsigned short* p_w = &p_sh[w][0][0];

  const float NEGINF = -__builtin_inff();
  float ml[2] = {NEGINF, NEGINF};
  float ll[2] = {0.f, 0.f};
  f32x4 o[2][4];
#pragma unroll
  for (int qt = 0; qt < 2; ++qt)
#pragma unroll
    for (int t = 0; t < 4; ++t) o[qt][t] = (f32x4){0.f, 0.f, 0.f, 0.f};

  const int NI = 2 * qt_blk + 2;
  int cur = 0;
  for (int i = 0; i < NI; ++i) {
    const int kv0 = i * 64;
    if (i + 1 < NI) { stK(cur ^ 1, kv0 + 64); stV(cur ^ 1, kv0 + 64); }

    const bool active = (kv0 <= qq0 + 31);
    if (active) {
      // ---- S^T = K * Q^T  (16 MFMA) ----
      f32x4 sacc[2][4];
#pragma unroll
      for (int qt = 0; qt < 2; ++qt)
#pragma unroll
        for (int t = 0; t < 4; ++t) sacc[qt][t] = (f32x4){0.f, 0.f, 0.f, 0.f};
      const char* kb = (const char*)k_sh[cur];
      __builtin_amdgcn_s_setprio(1);
#pragma unroll
      for (int t = 0; t < 4; ++t) {
        int sr = 16 * t + l15;
        int sw = (sr & 7) << 4;
        short8 kf0 = *(const short8*)(kb + sr * 128 + ((16 * lg) ^ sw));
        short8 kf1 = *(const short8*)(kb + sr * 128 + ((64 + 16 * lg) ^ sw));
#pragma unroll
        for (int qt = 0; qt < 2; ++qt) {
          sacc[qt][t] = __builtin_amdgcn_mfma_f32_16x16x32_bf16(kf0, qf[qt][0], sacc[qt][t], 0, 0, 0);
          sacc[qt][t] = __builtin_amdgcn_mfma_f32_16x16x32_bf16(kf1, qf[qt][1], sacc[qt][t], 0, 0, 0);
        }
      }
      __builtin_amdgcn_s_setprio(0);

      // ---- online softmax per q-tile (in-register, T13 defer-max) ----
      float corr[2];
      bool defer[2];
#pragma unroll
      for (int qt = 0; qt < 2; ++qt) {
        const bool nomask = (kv0 + 63) <= (qq0 + 16 * qt);   // wave-uniform
        float sv[16];
        if (nomask) {
#pragma unroll
          for (int t = 0; t < 4; ++t)
#pragma unroll
            for (int r = 0; r < 4; ++r) sv[4 * t + r] = sacc[qt][t][r];
        } else {
          const int qg = qq0 + 16 * qt + l15;
#pragma unroll
          for (int t = 0; t < 4; ++t)
#pragma unroll
            for (int r = 0; r < 4; ++r) {
              int sg = kv0 + 16 * t + 4 * lg + r;
              sv[4 * t + r] = (sg <= qg) ? sacc[qt][t][r] : NEGINF;
            }
        }
        float a8[8], a4[4], a2[2];
#pragma unroll
        for (int k = 0; k < 8; ++k) a8[k] = fmaxf(sv[k], sv[k + 8]);
#pragma unroll
        for (int k = 0; k < 4; ++k) a4[k] = fmaxf(a8[k], a8[k + 4]);
        a2[0] = fmaxf(a4[0], a4[2]); a2[1] = fmaxf(a4[1], a4[3]);
        float mx = fmaxf(a2[0], a2[1]);
        mx = fmaxf(mx, __shfl_xor(mx, 16));
        mx = fmaxf(mx, __shfl_xor(mx, 32));
        // T13: keep old max when growth small (P bounded by 2^(8*SCL2) ~ 2.7)
        defer[qt] = (__all(mx <= ml[qt] + 8.0f) != 0);
        float mnew = defer[qt] ? ml[qt] : fmaxf(ml[qt], mx);
        corr[qt] = defer[qt] ? 1.0f : EXP2F((ml[qt] - mnew) * SCL2);
        float nms2 = mnew * SCL2;
        float pv[16];
#pragma unroll
        for (int k = 0; k < 16; ++k) pv[k] = EXP2F(fmaf(sv[k], SCL2, -nms2));
        float s8[8], s4[4], s2[2];
#pragma unroll
        for (int k = 0; k < 8; ++k) s8[k] = pv[k] + pv[k + 8];
#pragma unroll
        for (int k = 0; k < 4; ++k) s4[k] = s8[k] + s8[k + 4];
        s2[0] = s4[0] + s4[2]; s2[1] = s4[1] + s4[3];
        float ps = s2[0] + s2[1];
        ps += __shfl_xor(ps, 16);
        ps += __shfl_xor(ps, 32);
        ll[qt] = ll[qt] * corr[qt] + ps;
        ml[qt] = mnew;
        // pack P -> LDS via v_cvt_pk_bf16_f32 (RNE, lo=src0)
#pragma unroll
        for (int t = 0; t < 4; ++t) {
          unsigned lo, hi;
          asm("v_cvt_pk_bf16_f32 %0, %1, %2" : "=v"(lo) : "v"(pv[4 * t]), "v"(pv[4 * t + 1]));
          asm("v_cvt_pk_bf16_f32 %0, %1, %2" : "=v"(hi) : "v"(pv[4 * t + 2]), "v"(pv[4 * t + 3]));
          u32x2 pk = {lo, hi};
          *(u32x2*)(void*)(p_w + (16 * qt + l15) * 72 + 16 * t + 4 * lg) = pk;
        }
      }
      asm volatile("" ::: "memory");  // order P stores before P frag loads

      // ---- rescale O (skipped when deferred) ----
#pragma unroll
      for (int qt = 0; qt < 2; ++qt)
        if (!defer[qt]) {
#pragma unroll
          for (int r = 0; r < 4; ++r) {
            float cr = __shfl(corr[qt], 4 * lg + r);
#pragma unroll
            for (int t = 0; t < 4; ++t) o[qt][t][r] *= cr;
          }
        }

      // ---- O += P * V  (16 MFMA) ----
      short8 pa[2][2];
#pragma unroll
      for (int qt = 0; qt < 2; ++qt)
#pragma unroll
        for (int kk = 0; kk < 2; ++kk)
          pa[qt][kk] = *(const short8*)(p_w + (16 * qt + l15) * 72 + kk * 32 + 8 * lg);

      const char* vbT = (const char*)v_sh[cur];
      __builtin_amdgcn_s_setprio(1);
#pragma unroll
      for (int t = 0; t < 4; ++t) {
        int dr = 16 * t + l15;
        int sw = (dr & 7) << 4;
        short8 vf0 = *(const short8*)(vbT + dr * 128 + ((16 * lg) ^ sw));
        short8 vf1 = *(const short8*)(vbT + dr * 128 + ((64 + 16 * lg) ^ sw));
#pragma unroll
        for (int qt = 0; qt < 2; ++qt) {
          o[qt][t] = __builtin_amdgcn_mfma_f32_16x16x32_bf16(pa[qt][0], vf0, o[qt][t], 0, 0, 0);
          o[qt][t] = __builtin_amdgcn_mfma_f32_16x16x32_bf16(pa[qt][1], vf1, o[qt][t], 0, 0, 0);
        }
      }
      __builtin_amdgcn_s_setprio(0);
    }
    __syncthreads();
    cur ^= 1;
  }

  // ---- epilogue: Y[b, q, h*64 + d] = O / l ----
#pragma unroll
  for (int qt = 0; qt < 2; ++qt) {
    float linv = 1.0f / ll[qt];
#pragma unroll
    for (int r = 0; r < 4; ++r) {
      float li = __shfl(linv, 4 * lg + r);
      int qg = qq0 + 16 * qt + 4 * lg + r;
      unsigned short* Yp = Y + ((size_t)(b * T_ + qg)) * D_ + h * 64;
#pragma unroll
      for (int t = 0; t < 4; ++t)
        Yp[16 * t + l15] = f2bf(o[qt][t][r] * li);
    }
  }
}

// ---------------- launch ----------------
extern "C" void kernel_launch(void* const* d_in, const int* in_sizes, int n_in,
                              void* d_out, int out_size, void* d_ws, size_t ws_size,
                              hipStream_t stream) {
  const float* x  = (const float*)d_in[0];
  const float* Wq = (const float*)d_in[1];
  const float* Wk = (const float*)d_in[2];
  const float* Wv = (const float*)d_in[3];
  const float* Wo = (const float*)d_in[4];
  float* out = (float*)d_out;

  const size_t NX = (size_t)M_ * D_;
  const size_t NW = (size_t)D_ * D_;
  const size_t need = (4 * NX + 4 * NW) * sizeof(unsigned short);
  if (ws_size < need) return;

  unsigned short* ws  = (unsigned short*)d_ws;
  unsigned short* xb  = ws;
  unsigned short* wqb = xb + NX;   // wqb/wkb/wvb contiguous = stacked QKV weight
  unsigned short* wkb = wqb + NW;
  unsigned short* wvb = wkb + NW;
  unsigned short* wob = wvb + NW;
  unsigned short* Qb  = wob + NW;  // Qb/Kb/Vtb contiguous = fused-QKV output
  unsigned short* Yb  = xb;        // alias: x dead after QKV projections

  cvt_bf16<<<(int)(NX / 1024), 256, 0, stream>>>(x, xb, (int)NX);
  cvt_w4<<<4096, 256, 0, stream>>>(Wq, Wk, Wv, Wo, wqb, wkb, wvb, wob);

  // fused QKV projection: C[8192, 3072] = x @ [Wq;Wk;Wv]^T
  gemm_bt<3><<<(M_ / 128) * (3072 / 128), 256, 0, stream>>>(xb, wqb, Qb, M_, 3072, D_);

  attn<<<B_ * H_ * (T_ / 128), 256, 0, stream>>>(Qb, Qb + NX, Qb + 2 * NX, Yb);

  gemm_bt<1><<<(M_ / 128) * (D_ / 128), 256, 0, stream>>>(Yb, wob, out, M_, D_, D_);
}

// Round 11
// 175.842 us; speedup vs baseline: 3.0397x; 1.0001x over previous
//
#include <hip/hip_runtime.h>

typedef __attribute__((ext_vector_type(8))) short short8;
typedef __attribute__((ext_vector_type(4))) float f32x4;
typedef __attribute__((ext_vector_type(2))) unsigned int u32x2;

constexpr int B_ = 4, T_ = 2048, D_ = 1024, H_ = 16;
constexpr int M_ = B_ * T_;          // 8192 token rows
constexpr float SCL2 = 0.1803368801111f;  // (1/sqrt(64)) * log2(e)

#if __has_builtin(__builtin_amdgcn_exp2f)
#define EXP2F __builtin_amdgcn_exp2f
#else
#define EXP2F exp2f
#endif

#define DEV __device__ __forceinline__

DEV unsigned short f2bf(float f) {   // f32 -> bf16 RNE
  unsigned int u = __builtin_bit_cast(unsigned int, f);
  u += 0x7FFFu + ((u >> 16) & 1u);
  return (unsigned short)(u >> 16);
}

DEV void gload16(const unsigned short* g, unsigned short* l) {
  __builtin_amdgcn_global_load_lds(
      (const __attribute__((address_space(1))) unsigned int*)g,
      (__attribute__((address_space(3))) unsigned int*)l, 16, 0, 0);
}

// ---------------- f32 -> bf16 conversion ----------------
__global__ __launch_bounds__(256) void cvt_bf16(const float* __restrict__ in,
                                                unsigned short* __restrict__ out,
                                                int n) {
  int i = (blockIdx.x * 256 + threadIdx.x) * 4;
  if (i >= n) return;
  float4 f = *(const float4*)(in + i);
  ushort4 o;
  o.x = f2bf(f.x); o.y = f2bf(f.y); o.z = f2bf(f.z); o.w = f2bf(f.w);
  *(ushort4*)(out + i) = o;
}

// 4 weights in one launch (1024 blocks each)
__global__ __launch_bounds__(256) void cvt_w4(const float* __restrict__ w0, const float* __restrict__ w1,
                                              const float* __restrict__ w2, const float* __restrict__ w3,
                                              unsigned short* __restrict__ o0, unsigned short* __restrict__ o1,
                                              unsigned short* __restrict__ o2, unsigned short* __restrict__ o3) {
  int sel = blockIdx.x >> 10;
  const float* in = sel == 0 ? w0 : sel == 1 ? w1 : sel == 2 ? w2 : w3;
  unsigned short* out = sel == 0 ? o0 : sel == 1 ? o1 : sel == 2 ? o2 : o3;
  int i = ((blockIdx.x & 1023) * 256 + threadIdx.x) * 4;
  float4 f = *(const float4*)(in + i);
  ushort4 o;
  o.x = f2bf(f.x); o.y = f2bf(f.y); o.z = f2bf(f.z); o.w = f2bf(f.w);
  *(ushort4*)(out + i) = o;
}

// ---------------- GEMM: C[M,N] = A[M,K] * B[N,K]^T ----------------
// OUTMODE: 0 = bf16 row-major, 1 = f32 row-major,
//          3 = fused QKV: region by tn (0-7 Q, 8-15 K, 16-23 Vt-per-head)
// T1 XCD swizzle: grid must be a multiple of 8 (1536 and 512 both are).
// (256,4): 4 blocks/CU residency — kernel fits (VGPR 56 + AGPR 64 <= 128/wave),
// needed to hide the per-iteration vmcnt(0) barrier drain (r10: 2.6 blocks/CU).
template <int OUTMODE>
__global__ __launch_bounds__(256, 4) void gemm_bt(const unsigned short* __restrict__ A,
                                                  const unsigned short* __restrict__ B,
                                                  void* __restrict__ C,
                                                  int M, int N, int K) {
  constexpr int BM = 128, BN = 128, BK = 32;
  __shared__ __align__(16) unsigned short a_sh[2 * BM * BK];
  __shared__ __align__(16) unsigned short b_sh[2 * BN * BK];

  const int tid = threadIdx.x;
  const int lane = tid & 63;
  const int w = tid >> 6;
  const int l15 = lane & 15, lg = lane >> 4;
  const int wr = w >> 1, wc = w & 1;

  // XCD-chunked bijective swizzle: each XCD gets a contiguous run of tiles
  const int nwg = gridDim.x;
  const int swz = (blockIdx.x & 7) * (nwg >> 3) + (blockIdx.x >> 3);

  const int NT = N / BN;
  const int tm = swz / NT, tn = swz % NT;
  const unsigned short* Ab = A + (size_t)tm * BM * K;
  const unsigned short* Bb = B + (size_t)tn * BN * K;

  f32x4 acc[4][4];
#pragma unroll
  for (int m = 0; m < 4; ++m)
#pragma unroll
    for (int n = 0; n < 4; ++n) acc[m][n] = (f32x4){0.f, 0.f, 0.f, 0.f};

  auto stage = [&](int buf, int kt) {
    int k0 = kt * BK;
#pragma unroll
    for (int rnd = 0; rnd < 2; ++rnd) {
      int c = rnd * 256 + tid;
      int row = c >> 2, cc = (c & 3) * 8;
      gload16(Ab + (size_t)row * K + k0 + cc,
              a_sh + buf * BM * BK + rnd * 2048 + w * 512);
      gload16(Bb + (size_t)row * K + k0 + cc,
              b_sh + buf * BN * BK + rnd * 2048 + w * 512);
    }
  };

  stage(0, 0);
  int cur = 0;
  const int NK = K / BK;
  for (int kt = 0; kt < NK; ++kt) {
    __syncthreads();
    if (kt + 1 < NK) stage(cur ^ 1, kt + 1);
    const unsigned short* ab = a_sh + cur * BM * BK;
    const unsigned short* bb = b_sh + cur * BN * BK;
    short8 af[4], bf8[4];
#pragma unroll
    for (int m = 0; m < 4; ++m)
      af[m] = *(const short8*)(ab + (wr * 64 + m * 16 + l15) * BK + lg * 8);
#pragma unroll
    for (int n = 0; n < 4; ++n)
      bf8[n] = *(const short8*)(bb + (wc * 64 + n * 16 + l15) * BK + lg * 8);
#pragma unroll
    for (int m = 0; m < 4; ++m)
#pragma unroll
      for (int n = 0; n < 4; ++n)
        acc[m][n] = __builtin_amdgcn_mfma_f32_16x16x32_bf16(af[m], bf8[n], acc[m][n], 0, 0, 0);
    cur ^= 1;
  }

  const int row0 = tm * BM + wr * 64 + lg * 4;
  const int col0 = tn * BN + wc * 64 + l15;
#pragma unroll
  for (int m = 0; m < 4; ++m)
#pragma unroll
    for (int n = 0; n < 4; ++n) {
      if (OUTMODE == 3) {
        const int region = tn >> 3;               // 0=Q, 1=K, 2=V
        const int nc = col0 - (region << 10) + n * 16;
        const int mm = row0 + m * 16;
        if (region == 2) {
          // Vt-per-head: [(b*16+h)][d][s], r consecutive in s
          size_t base = (size_t)2 * 8388608 +
                        ((size_t)((mm >> 11) * 16 + (nc >> 6))) * 131072 +
                        (size_t)(nc & 63) * 2048 + (mm & 2047);
          ushort4 pk;
          pk.x = f2bf(acc[m][n][0]); pk.y = f2bf(acc[m][n][1]);
          pk.z = f2bf(acc[m][n][2]); pk.w = f2bf(acc[m][n][3]);
          *(ushort4*)((unsigned short*)C + base) = pk;
        } else {
          unsigned short* dst = (unsigned short*)C + (size_t)region * 8388608;
#pragma unroll
          for (int r = 0; r < 4; ++r)
            dst[(size_t)(mm + r) * 1024 + nc] = f2bf(acc[m][n][r]);
        }
      } else {
#pragma unroll
        for (int r = 0; r < 4; ++r) {
          size_t idx = (size_t)(row0 + m * 16 + r) * N + (col0 + n * 16);
          if (OUTMODE == 1)
            ((float*)C)[idx] = acc[m][n][r];
          else
            ((unsigned short*)C)[idx] = f2bf(acc[m][n][r]);
        }
      }
    }
}

// ---------------- causal flash attention (swapped-QK, KB=64, QB=128) --------
// Round-10 structure (round-7 + T13 defer-max) — unchanged this round.
__global__ __launch_bounds__(256, 3) void attn(const unsigned short* __restrict__ Q,
                                               const unsigned short* __restrict__ K,
                                               const unsigned short* __restrict__ Vt,
                                               unsigned short* __restrict__ Y) {
  __shared__ __align__(16) unsigned short k_sh[2][64 * 64];
  __shared__ __align__(16) unsigned short v_sh[2][64 * 64];   // [d][s], swizzled
  __shared__ __align__(16) unsigned short p_sh[4][32][72];    // per-wave P

  const int tid = threadIdx.x;
  const int lane = tid & 63;
  const int w = tid >> 6;
  const int l15 = lane & 15, lg = lane >> 4;

  const int bid = blockIdx.x;
  const int qt_blk = 15 - (bid >> 6);          // all heavy blocks dispatch first
  const int bh = bid & 63;
  const int h = bh & 15;
  const int b = bh >> 4;
  const int q0 = qt_blk * 128;
  const int qq0 = q0 + 32 * w;                 // this wave's first q-row

  const unsigned short* Qp = Q + ((size_t)(b * T_ + q0)) * D_ + h * 64;
  const unsigned short* Kp = K + ((size_t)(b * T_)) * D_ + h * 64;
  const unsigned short* Vtp = Vt + (size_t)bh * 131072;   // [64 d][2048 s]

  auto stK = [&](int buf, int kv0) {
#pragma unroll
    for (int j = 0; j < 2; ++j) {
      int c = j * 256 + tid;
      int row = c >> 3;
      gload16(Kp + (size_t)(kv0 + row) * D_ + 8 * ((c & 7) ^ (row & 7)),
              &k_sh[buf][(j * 256 + w * 64) * 8]);
    }
  };
  auto stV = [&](int buf, int kv0) {
#pragma unroll
    for (int j = 0; j < 2; ++j) {
      int c = j * 256 + tid;
      int d = c >> 3;
      gload16(Vtp + (size_t)d * 2048 + kv0 + 8 * ((c & 7) ^ (d & 7)),
              &v_sh[buf][(j * 256 + w * 64) * 8]);
    }
  };

  // Q fragments direct global -> registers (B-frag: row = q, k-contig)
  short8 qf[2][2];
#pragma unroll
  for (int qt = 0; qt < 2; ++qt)
#pragma unroll
    for (int kk = 0; kk < 2; ++kk)
      qf[qt][kk] = *(const short8*)(Qp + (size_t)(32 * w + 16 * qt + l15) * D_ + 32 * kk + 8 * lg);

  stK(0, 0);
  stV(0, 0);
  __syncthreads();

  unsigned short* p_w = &p_sh[w][0][0];

  const float NEGINF = -__builtin_inff();
  float ml[2] = {NEGINF, NEGINF};
  float ll[2] = {0.f, 0.f};
  f32x4 o[2][4];
#pragma unroll
  for (int qt = 0; qt < 2; ++qt)
#pragma unroll
    for (int t = 0; t < 4; ++t) o[qt][t] = (f32x4){0.f, 0.f, 0.f, 0.f};

  const int NI = 2 * qt_blk + 2;
  int cur = 0;
  for (int i = 0; i < NI; ++i) {
    const int kv0 = i * 64;
    if (i + 1 < NI) { stK(cur ^ 1, kv0 + 64); stV(cur ^ 1, kv0 + 64); }

    const bool active = (kv0 <= qq0 + 31);
    if (active) {
      // ---- S^T = K * Q^T  (16 MFMA) ----
      f32x4 sacc[2][4];
#pragma unroll
      for (int qt = 0; qt < 2; ++qt)
#pragma unroll
        for (int t = 0; t < 4; ++t) sacc[qt][t] = (f32x4){0.f, 0.f, 0.f, 0.f};
      const char* kb = (const char*)k_sh[cur];
      __builtin_amdgcn_s_setprio(1);
#pragma unroll
      for (int t = 0; t < 4; ++t) {
        int sr = 16 * t + l15;
        int sw = (sr & 7) << 4;
        short8 kf0 = *(const short8*)(kb + sr * 128 + ((16 * lg) ^ sw));
        short8 kf1 = *(const short8*)(kb + sr * 128 + ((64 + 16 * lg) ^ sw));
#pragma unroll
        for (int qt = 0; qt < 2; ++qt) {
          sacc[qt][t] = __builtin_amdgcn_mfma_f32_16x16x32_bf16(kf0, qf[qt][0], sacc[qt][t], 0, 0, 0);
          sacc[qt][t] = __builtin_amdgcn_mfma_f32_16x16x32_bf16(kf1, qf[qt][1], sacc[qt][t], 0, 0, 0);
        }
      }
      __builtin_amdgcn_s_setprio(0);

      // ---- online softmax per q-tile (in-register, T13 defer-max) ----
      float corr[2];
      bool defer[2];
#pragma unroll
      for (int qt = 0; qt < 2; ++qt) {
        const bool nomask = (kv0 + 63) <= (qq0 + 16 * qt);   // wave-uniform
        float sv[16];
        if (nomask) {
#pragma unroll
          for (int t = 0; t < 4; ++t)
#pragma unroll
            for (int r = 0; r < 4; ++r) sv[4 * t + r] = sacc[qt][t][r];
        } else {
          const int qg = qq0 + 16 * qt + l15;
#pragma unroll
          for (int t = 0; t < 4; ++t)
#pragma unroll
            for (int r = 0; r < 4; ++r) {
              int sg = kv0 + 16 * t + 4 * lg + r;
              sv[4 * t + r] = (sg <= qg) ? sacc[qt][t][r] : NEGINF;
            }
        }
        float a8[8], a4[4], a2[2];
#pragma unroll
        for (int k = 0; k < 8; ++k) a8[k] = fmaxf(sv[k], sv[k + 8]);
#pragma unroll
        for (int k = 0; k < 4; ++k) a4[k] = fmaxf(a8[k], a8[k + 4]);
        a2[0] = fmaxf(a4[0], a4[2]); a2[1] = fmaxf(a4[1], a4[3]);
        float mx = fmaxf(a2[0], a2[1]);
        mx = fmaxf(mx, __shfl_xor(mx, 16));
        mx = fmaxf(mx, __shfl_xor(mx, 32));
        // T13: keep old max when growth small (P bounded by 2^(8*SCL2) ~ 2.7)
        defer[qt] = (__all(mx <= ml[qt] + 8.0f) != 0);
        float mnew = defer[qt] ? ml[qt] : fmaxf(ml[qt], mx);
        corr[qt] = defer[qt] ? 1.0f : EXP2F((ml[qt] - mnew) * SCL2);
        float nms2 = mnew * SCL2;
        float pv[16];
#pragma unroll
        for (int k = 0; k < 16; ++k) pv[k] = EXP2F(fmaf(sv[k], SCL2, -nms2));
        float s8[8], s4[4], s2[2];
#pragma unroll
        for (int k = 0; k < 8; ++k) s8[k] = pv[k] + pv[k + 8];
#pragma unroll
        for (int k = 0; k < 4; ++k) s4[k] = s8[k] + s8[k + 4];
        s2[0] = s4[0] + s4[2]; s2[1] = s4[1] + s4[3];
        float ps = s2[0] + s2[1];
        ps += __shfl_xor(ps, 16);
        ps += __shfl_xor(ps, 32);
        ll[qt] = ll[qt] * corr[qt] + ps;
        ml[qt] = mnew;
        // pack P -> LDS via v_cvt_pk_bf16_f32 (RNE, lo=src0)
#pragma unroll
        for (int t = 0; t < 4; ++t) {
          unsigned lo, hi;
          asm("v_cvt_pk_bf16_f32 %0, %1, %2" : "=v"(lo) : "v"(pv[4 * t]), "v"(pv[4 * t + 1]));
          asm("v_cvt_pk_bf16_f32 %0, %1, %2" : "=v"(hi) : "v"(pv[4 * t + 2]), "v"(pv[4 * t + 3]));
          u32x2 pk = {lo, hi};
          *(u32x2*)(void*)(p_w + (16 * qt + l15) * 72 + 16 * t + 4 * lg) = pk;
        }
      }
      asm volatile("" ::: "memory");  // order P stores before P frag loads

      // ---- rescale O (skipped when deferred) ----
#pragma unroll
      for (int qt = 0; qt < 2; ++qt)
        if (!defer[qt]) {
#pragma unroll
          for (int r = 0; r < 4; ++r) {
            float cr = __shfl(corr[qt], 4 * lg + r);
#pragma unroll
            for (int t = 0; t < 4; ++t) o[qt][t][r] *= cr;
          }
        }

      // ---- O += P * V  (16 MFMA) ----
      short8 pa[2][2];
#pragma unroll
      for (int qt = 0; qt < 2; ++qt)
#pragma unroll
        for (int kk = 0; kk < 2; ++kk)
          pa[qt][kk] = *(const short8*)(p_w + (16 * qt + l15) * 72 + kk * 32 + 8 * lg);

      const char* vbT = (const char*)v_sh[cur];
      __builtin_amdgcn_s_setprio(1);
#pragma unroll
      for (int t = 0; t < 4; ++t) {
        int dr = 16 * t + l15;
        int sw = (dr & 7) << 4;
        short8 vf0 = *(const short8*)(vbT + dr * 128 + ((16 * lg) ^ sw));
        short8 vf1 = *(const short8*)(vbT + dr * 128 + ((64 + 16 * lg) ^ sw));
#pragma unroll
        for (int qt = 0; qt < 2; ++qt) {
          o[qt][t] = __builtin_amdgcn_mfma_f32_16x16x32_bf16(pa[qt][0], vf0, o[qt][t], 0, 0, 0);
          o[qt][t] = __builtin_amdgcn_mfma_f32_16x16x32_bf16(pa[qt][1], vf1, o[qt][t], 0, 0, 0);
        }
      }
      __builtin_amdgcn_s_setprio(0);
    }
    __syncthreads();
    cur ^= 1;
  }

  // ---- epilogue: Y[b, q, h*64 + d] = O / l ----
#pragma unroll
  for (int qt = 0; qt < 2; ++qt) {
    float linv = 1.0f / ll[qt];
#pragma unroll
    for (int r = 0; r < 4; ++r) {
      float li = __shfl(linv, 4 * lg + r);
      int qg = qq0 + 16 * qt + 4 * lg + r;
      unsigned short* Yp = Y + ((size_t)(b * T_ + qg)) * D_ + h * 64;
#pragma unroll
      for (int t = 0; t < 4; ++t)
        Yp[16 * t + l15] = f2bf(o[qt][t][r] * li);
    }
  }
}

// ---------------- launch ----------------
extern "C" void kernel_launch(void* const* d_in, const int* in_sizes, int n_in,
                              void* d_out, int out_size, void* d_ws, size_t ws_size,
                              hipStream_t stream) {
  const float* x  = (const float*)d_in[0];
  const float* Wq = (const float*)d_in[1];
  const float* Wk = (const float*)d_in[2];
  const float* Wv = (const float*)d_in[3];
  const float* Wo = (const float*)d_in[4];
  float* out = (float*)d_out;

  const size_t NX = (size_t)M_ * D_;
  const size_t NW = (size_t)D_ * D_;
  const size_t need = (4 * NX + 4 * NW) * sizeof(unsigned short);
  if (ws_size < need) return;

  unsigned short* ws  = (unsigned short*)d_ws;
  unsigned short* xb  = ws;
  unsigned short* wqb = xb + NX;   // wqb/wkb/wvb contiguous = stacked QKV weight
  unsigned short* wkb = wqb + NW;
  unsigned short* wvb = wkb + NW;
  unsigned short* wob = wvb + NW;
  unsigned short* Qb  = wob + NW;  // Qb/Kb/Vtb contiguous = fused-QKV output
  unsigned short* Yb  = xb;        // alias: x dead after QKV projections

  cvt_bf16<<<(int)(NX / 1024), 256, 0, stream>>>(x, xb, (int)NX);
  cvt_w4<<<4096, 256, 0, stream>>>(Wq, Wk, Wv, Wo, wqb, wkb, wvb, wob);

  // fused QKV projection: C[8192, 3072] = x @ [Wq;Wk;Wv]^T
  gemm_bt<3><<<(M_ / 128) * (3072 / 128), 256, 0, stream>>>(xb, wqb, Qb, M_, 3072, D_);

  attn<<<B_ * H_ * (T_ / 128), 256, 0, stream>>>(Qb, Qb + NX, Qb + 2 * NX, Yb);

  gemm_bt<1><<<(M_ / 128) * (D_ / 128), 256, 0, stream>>>(Yb, wob, out, M_, D_, D_);
}

// Round 12
// 175.683 us; speedup vs baseline: 3.0424x; 1.0009x over previous
//
#include <hip/hip_runtime.h>

typedef __attribute__((ext_vector_type(8))) short short8;
typedef __attribute__((ext_vector_type(4))) float f32x4;
typedef __attribute__((ext_vector_type(2))) unsigned int u32x2;

constexpr int B_ = 4, T_ = 2048, D_ = 1024, H_ = 16;
constexpr int M_ = B_ * T_;          // 8192 token rows
constexpr float SCL2 = 0.1803368801111f;  // (1/sqrt(64)) * log2(e)

#if __has_builtin(__builtin_amdgcn_exp2f)
#define EXP2F __builtin_amdgcn_exp2f
#else
#define EXP2F exp2f
#endif

#define DEV __device__ __forceinline__

DEV unsigned short f2bf(float f) {   // f32 -> bf16 RNE
  unsigned int u = __builtin_bit_cast(unsigned int, f);
  u += 0x7FFFu + ((u >> 16) & 1u);
  return (unsigned short)(u >> 16);
}

DEV void gload16(const unsigned short* g, unsigned short* l) {
  __builtin_amdgcn_global_load_lds(
      (const __attribute__((address_space(1))) unsigned int*)g,
      (__attribute__((address_space(3))) unsigned int*)l, 16, 0, 0);
}

// ---------------- f32 -> bf16 conversion ----------------
__global__ __launch_bounds__(256) void cvt_bf16(const float* __restrict__ in,
                                                unsigned short* __restrict__ out,
                                                int n) {
  int i = (blockIdx.x * 256 + threadIdx.x) * 4;
  if (i >= n) return;
  float4 f = *(const float4*)(in + i);
  ushort4 o;
  o.x = f2bf(f.x); o.y = f2bf(f.y); o.z = f2bf(f.z); o.w = f2bf(f.w);
  *(ushort4*)(out + i) = o;
}

// 4 weights in one launch (1024 blocks each)
__global__ __launch_bounds__(256) void cvt_w4(const float* __restrict__ w0, const float* __restrict__ w1,
                                              const float* __restrict__ w2, const float* __restrict__ w3,
                                              unsigned short* __restrict__ o0, unsigned short* __restrict__ o1,
                                              unsigned short* __restrict__ o2, unsigned short* __restrict__ o3) {
  int sel = blockIdx.x >> 10;
  const float* in = sel == 0 ? w0 : sel == 1 ? w1 : sel == 2 ? w2 : w3;
  unsigned short* out = sel == 0 ? o0 : sel == 1 ? o1 : sel == 2 ? o2 : o3;
  int i = ((blockIdx.x & 1023) * 256 + threadIdx.x) * 4;
  float4 f = *(const float4*)(in + i);
  ushort4 o;
  o.x = f2bf(f.x); o.y = f2bf(f.y); o.z = f2bf(f.z); o.w = f2bf(f.w);
  *(ushort4*)(out + i) = o;
}

// ---------------- GEMM: C[M,N] = A[M,K] * B[N,K]^T ----------------
// OUTMODE: 0 = bf16 row-major, 1 = f32 row-major,
//          3 = fused QKV: region by tn (0-7 Q, 8-15 K, 16-23 Vt-per-head)
// T4 counted-vmcnt K-loop: 4 LDS buffers, prefetch depth 2, raw s_barrier
// (no vmcnt(0) drain in steady state). Race audit: wave skew <= 1 iter;
// writes hit buf (kt+2)&3 while reads hit (kt-1)&3 / kt&3 — distance 3/2 mod 4.
template <int OUTMODE>
__global__ __launch_bounds__(256, 2) void gemm_bt(const unsigned short* __restrict__ A,
                                                  const unsigned short* __restrict__ B,
                                                  void* __restrict__ C,
                                                  int M, int N, int K) {
  constexpr int BM = 128, BN = 128, BK = 32;
  __shared__ __align__(16) unsigned short a_sh[4 * BM * BK];  // 32 KB
  __shared__ __align__(16) unsigned short b_sh[4 * BN * BK];  // 32 KB

  const int tid = threadIdx.x;
  const int lane = tid & 63;
  const int w = tid >> 6;
  const int l15 = lane & 15, lg = lane >> 4;
  const int wr = w >> 1, wc = w & 1;

  // XCD-chunked bijective swizzle: each XCD gets a contiguous run of tiles
  const int nwg = gridDim.x;
  const int swz = (blockIdx.x & 7) * (nwg >> 3) + (blockIdx.x >> 3);

  const int NT = N / BN;
  const int tm = swz / NT, tn = swz % NT;
  const unsigned short* Ab = A + (size_t)tm * BM * K;
  const unsigned short* Bb = B + (size_t)tn * BN * K;

  f32x4 acc[4][4];
#pragma unroll
  for (int m = 0; m < 4; ++m)
#pragma unroll
    for (int n = 0; n < 4; ++n) acc[m][n] = (f32x4){0.f, 0.f, 0.f, 0.f};

  auto stage = [&](int buf, int kt) {
    int k0 = kt * BK;
#pragma unroll
    for (int rnd = 0; rnd < 2; ++rnd) {
      int c = rnd * 256 + tid;
      int row = c >> 2, cc = (c & 3) * 8;
      gload16(Ab + (size_t)row * K + k0 + cc,
              a_sh + buf * BM * BK + rnd * 2048 + w * 512);
      gload16(Bb + (size_t)row * K + k0 + cc,
              b_sh + buf * BN * BK + rnd * 2048 + w * 512);
    }
  };

  const int NK = K / BK;
  stage(0, 0);
  stage(1, 1);
  for (int kt = 0; kt < NK; ++kt) {
    if (kt + 2 < NK) stage((kt + 2) & 3, kt + 2);
    __builtin_amdgcn_sched_barrier(0);
    // counted wait: 4 loads/tile; oldest tile (kt) must have landed.
    if (kt + 2 < NK)      asm volatile("s_waitcnt vmcnt(8)" ::: "memory");
    else if (kt + 1 < NK) asm volatile("s_waitcnt vmcnt(4)" ::: "memory");
    else                  asm volatile("s_waitcnt vmcnt(0)" ::: "memory");
    __builtin_amdgcn_s_barrier();
    __builtin_amdgcn_sched_barrier(0);

    const int cur = kt & 3;
    const unsigned short* ab = a_sh + cur * BM * BK;
    const unsigned short* bb = b_sh + cur * BN * BK;
    short8 af[4], bf8[4];
#pragma unroll
    for (int m = 0; m < 4; ++m)
      af[m] = *(const short8*)(ab + (wr * 64 + m * 16 + l15) * BK + lg * 8);
#pragma unroll
    for (int n = 0; n < 4; ++n)
      bf8[n] = *(const short8*)(bb + (wc * 64 + n * 16 + l15) * BK + lg * 8);
#pragma unroll
    for (int m = 0; m < 4; ++m)
#pragma unroll
      for (int n = 0; n < 4; ++n)
        acc[m][n] = __builtin_amdgcn_mfma_f32_16x16x32_bf16(af[m], bf8[n], acc[m][n], 0, 0, 0);
  }

  const int row0 = tm * BM + wr * 64 + lg * 4;
  const int col0 = tn * BN + wc * 64 + l15;
#pragma unroll
  for (int m = 0; m < 4; ++m)
#pragma unroll
    for (int n = 0; n < 4; ++n) {
      if (OUTMODE == 3) {
        const int region = tn >> 3;               // 0=Q, 1=K, 2=V
        const int nc = col0 - (region << 10) + n * 16;
        const int mm = row0 + m * 16;
        if (region == 2) {
          // Vt-per-head: [(b*16+h)][d][s], r consecutive in s
          size_t base = (size_t)2 * 8388608 +
                        ((size_t)((mm >> 11) * 16 + (nc >> 6))) * 131072 +
                        (size_t)(nc & 63) * 2048 + (mm & 2047);
          ushort4 pk;
          pk.x = f2bf(acc[m][n][0]); pk.y = f2bf(acc[m][n][1]);
          pk.z = f2bf(acc[m][n][2]); pk.w = f2bf(acc[m][n][3]);
          *(ushort4*)((unsigned short*)C + base) = pk;
        } else {
          unsigned short* dst = (unsigned short*)C + (size_t)region * 8388608;
#pragma unroll
          for (int r = 0; r < 4; ++r)
            dst[(size_t)(mm + r) * 1024 + nc] = f2bf(acc[m][n][r]);
        }
      } else {
#pragma unroll
        for (int r = 0; r < 4; ++r) {
          size_t idx = (size_t)(row0 + m * 16 + r) * N + (col0 + n * 16);
          if (OUTMODE == 1)
            ((float*)C)[idx] = acc[m][n][r];
          else
            ((unsigned short*)C)[idx] = f2bf(acc[m][n][r]);
        }
      }
    }
}

// ---------------- causal flash attention (swapped-QK, KB=64, QB=128) --------
// Round-10 structure (round-7 + T13 defer-max) — unchanged this round.
__global__ __launch_bounds__(256, 3) void attn(const unsigned short* __restrict__ Q,
                                               const unsigned short* __restrict__ K,
                                               const unsigned short* __restrict__ Vt,
                                               unsigned short* __restrict__ Y) {
  __shared__ __align__(16) unsigned short k_sh[2][64 * 64];
  __shared__ __align__(16) unsigned short v_sh[2][64 * 64];   // [d][s], swizzled
  __shared__ __align__(16) unsigned short p_sh[4][32][72];    // per-wave P

  const int tid = threadIdx.x;
  const int lane = tid & 63;
  const int w = tid >> 6;
  const int l15 = lane & 15, lg = lane >> 4;

  const int bid = blockIdx.x;
  const int qt_blk = 15 - (bid >> 6);          // all heavy blocks dispatch first
  const int bh = bid & 63;
  const int h = bh & 15;
  const int b = bh >> 4;
  const int q0 = qt_blk * 128;
  const int qq0 = q0 + 32 * w;                 // this wave's first q-row

  const unsigned short* Qp = Q + ((size_t)(b * T_ + q0)) * D_ + h * 64;
  const unsigned short* Kp = K + ((size_t)(b * T_)) * D_ + h * 64;
  const unsigned short* Vtp = Vt + (size_t)bh * 131072;   // [64 d][2048 s]

  auto stK = [&](int buf, int kv0) {
#pragma unroll
    for (int j = 0; j < 2; ++j) {
      int c = j * 256 + tid;
      int row = c >> 3;
      gload16(Kp + (size_t)(kv0 + row) * D_ + 8 * ((c & 7) ^ (row & 7)),
              &k_sh[buf][(j * 256 + w * 64) * 8]);
    }
  };
  auto stV = [&](int buf, int kv0) {
#pragma unroll
    for (int j = 0; j < 2; ++j) {
      int c = j * 256 + tid;
      int d = c >> 3;
      gload16(Vtp + (size_t)d * 2048 + kv0 + 8 * ((c & 7) ^ (d & 7)),
              &v_sh[buf][(j * 256 + w * 64) * 8]);
    }
  };

  // Q fragments direct global -> registers (B-frag: row = q, k-contig)
  short8 qf[2][2];
#pragma unroll
  for (int qt = 0; qt < 2; ++qt)
#pragma unroll
    for (int kk = 0; kk < 2; ++kk)
      qf[qt][kk] = *(const short8*)(Qp + (size_t)(32 * w + 16 * qt + l15) * D_ + 32 * kk + 8 * lg);

  stK(0, 0);
  stV(0, 0);
  __syncthreads();

  unsigned short* p_w = &p_sh[w][0][0];

  const float NEGINF = -__builtin_inff();
  float ml[2] = {NEGINF, NEGINF};
  float ll[2] = {0.f, 0.f};
  f32x4 o[2][4];
#pragma unroll
  for (int qt = 0; qt < 2; ++qt)
#pragma unroll
    for (int t = 0; t < 4; ++t) o[qt][t] = (f32x4){0.f, 0.f, 0.f, 0.f};

  const int NI = 2 * qt_blk + 2;
  int cur = 0;
  for (int i = 0; i < NI; ++i) {
    const int kv0 = i * 64;
    if (i + 1 < NI) { stK(cur ^ 1, kv0 + 64); stV(cur ^ 1, kv0 + 64); }

    const bool active = (kv0 <= qq0 + 31);
    if (active) {
      // ---- S^T = K * Q^T  (16 MFMA) ----
      f32x4 sacc[2][4];
#pragma unroll
      for (int qt = 0; qt < 2; ++qt)
#pragma unroll
        for (int t = 0; t < 4; ++t) sacc[qt][t] = (f32x4){0.f, 0.f, 0.f, 0.f};
      const char* kb = (const char*)k_sh[cur];
      __builtin_amdgcn_s_setprio(1);
#pragma unroll
      for (int t = 0; t < 4; ++t) {
        int sr = 16 * t + l15;
        int sw = (sr & 7) << 4;
        short8 kf0 = *(const short8*)(kb + sr * 128 + ((16 * lg) ^ sw));
        short8 kf1 = *(const short8*)(kb + sr * 128 + ((64 + 16 * lg) ^ sw));
#pragma unroll
        for (int qt = 0; qt < 2; ++qt) {
          sacc[qt][t] = __builtin_amdgcn_mfma_f32_16x16x32_bf16(kf0, qf[qt][0], sacc[qt][t], 0, 0, 0);
          sacc[qt][t] = __builtin_amdgcn_mfma_f32_16x16x32_bf16(kf1, qf[qt][1], sacc[qt][t], 0, 0, 0);
        }
      }
      __builtin_amdgcn_s_setprio(0);

      // ---- online softmax per q-tile (in-register, T13 defer-max) ----
      float corr[2];
      bool defer[2];
#pragma unroll
      for (int qt = 0; qt < 2; ++qt) {
        const bool nomask = (kv0 + 63) <= (qq0 + 16 * qt);   // wave-uniform
        float sv[16];
        if (nomask) {
#pragma unroll
          for (int t = 0; t < 4; ++t)
#pragma unroll
            for (int r = 0; r < 4; ++r) sv[4 * t + r] = sacc[qt][t][r];
        } else {
          const int qg = qq0 + 16 * qt + l15;
#pragma unroll
          for (int t = 0; t < 4; ++t)
#pragma unroll
            for (int r = 0; r < 4; ++r) {
              int sg = kv0 + 16 * t + 4 * lg + r;
              sv[4 * t + r] = (sg <= qg) ? sacc[qt][t][r] : NEGINF;
            }
        }
        float a8[8], a4[4], a2[2];
#pragma unroll
        for (int k = 0; k < 8; ++k) a8[k] = fmaxf(sv[k], sv[k + 8]);
#pragma unroll
        for (int k = 0; k < 4; ++k) a4[k] = fmaxf(a8[k], a8[k + 4]);
        a2[0] = fmaxf(a4[0], a4[2]); a2[1] = fmaxf(a4[1], a4[3]);
        float mx = fmaxf(a2[0], a2[1]);
        mx = fmaxf(mx, __shfl_xor(mx, 16));
        mx = fmaxf(mx, __shfl_xor(mx, 32));
        // T13: keep old max when growth small (P bounded by 2^(8*SCL2) ~ 2.7)
        defer[qt] = (__all(mx <= ml[qt] + 8.0f) != 0);
        float mnew = defer[qt] ? ml[qt] : fmaxf(ml[qt], mx);
        corr[qt] = defer[qt] ? 1.0f : EXP2F((ml[qt] - mnew) * SCL2);
        float nms2 = mnew * SCL2;
        float pv[16];
#pragma unroll
        for (int k = 0; k < 16; ++k) pv[k] = EXP2F(fmaf(sv[k], SCL2, -nms2));
        float s8[8], s4[4], s2[2];
#pragma unroll
        for (int k = 0; k < 8; ++k) s8[k] = pv[k] + pv[k + 8];
#pragma unroll
        for (int k = 0; k < 4; ++k) s4[k] = s8[k] + s8[k + 4];
        s2[0] = s4[0] + s4[2]; s2[1] = s4[1] + s4[3];
        float ps = s2[0] + s2[1];
        ps += __shfl_xor(ps, 16);
        ps += __shfl_xor(ps, 32);
        ll[qt] = ll[qt] * corr[qt] + ps;
        ml[qt] = mnew;
        // pack P -> LDS via v_cvt_pk_bf16_f32 (RNE, lo=src0)
#pragma unroll
        for (int t = 0; t < 4; ++t) {
          unsigned lo, hi;
          asm("v_cvt_pk_bf16_f32 %0, %1, %2" : "=v"(lo) : "v"(pv[4 * t]), "v"(pv[4 * t + 1]));
          asm("v_cvt_pk_bf16_f32 %0, %1, %2" : "=v"(hi) : "v"(pv[4 * t + 2]), "v"(pv[4 * t + 3]));
          u32x2 pk = {lo, hi};
          *(u32x2*)(void*)(p_w + (16 * qt + l15) * 72 + 16 * t + 4 * lg) = pk;
        }
      }
      asm volatile("" ::: "memory");  // order P stores before P frag loads

      // ---- rescale O (skipped when deferred) ----
#pragma unroll
      for (int qt = 0; qt < 2; ++qt)
        if (!defer[qt]) {
#pragma unroll
          for (int r = 0; r < 4; ++r) {
            float cr = __shfl(corr[qt], 4 * lg + r);
#pragma unroll
            for (int t = 0; t < 4; ++t) o[qt][t][r] *= cr;
          }
        }

      // ---- O += P * V  (16 MFMA) ----
      short8 pa[2][2];
#pragma unroll
      for (int qt = 0; qt < 2; ++qt)
#pragma unroll
        for (int kk = 0; kk < 2; ++kk)
          pa[qt][kk] = *(const short8*)(p_w + (16 * qt + l15) * 72 + kk * 32 + 8 * lg);

      const char* vbT = (const char*)v_sh[cur];
      __builtin_amdgcn_s_setprio(1);
#pragma unroll
      for (int t = 0; t < 4; ++t) {
        int dr = 16 * t + l15;
        int sw = (dr & 7) << 4;
        short8 vf0 = *(const short8*)(vbT + dr * 128 + ((16 * lg) ^ sw));
        short8 vf1 = *(const short8*)(vbT + dr * 128 + ((64 + 16 * lg) ^ sw));
#pragma unroll
        for (int qt = 0; qt < 2; ++qt) {
          o[qt][t] = __builtin_amdgcn_mfma_f32_16x16x32_bf16(pa[qt][0], vf0, o[qt][t], 0, 0, 0);
          o[qt][t] = __builtin_amdgcn_mfma_f32_16x16x32_bf16(pa[qt][1], vf1, o[qt][t], 0, 0, 0);
        }
      }
      __builtin_amdgcn_s_setprio(0);
    }
    __syncthreads();
    cur ^= 1;
  }

  // ---- epilogue: Y[b, q, h*64 + d] = O / l ----
#pragma unroll
  for (int qt = 0; qt < 2; ++qt) {
    float linv = 1.0f / ll[qt];
#pragma unroll
    for (int r = 0; r < 4; ++r) {
      float li = __shfl(linv, 4 * lg + r);
      int qg = qq0 + 16 * qt + 4 * lg + r;
      unsigned short* Yp = Y + ((size_t)(b * T_ + qg)) * D_ + h * 64;
#pragma unroll
      for (int t = 0; t < 4; ++t)
        Yp[16 * t + l15] = f2bf(o[qt][t][r] * li);
    }
  }
}

// ---------------- launch ----------------
extern "C" void kernel_launch(void* const* d_in, const int* in_sizes, int n_in,
                              void* d_out, int out_size, void* d_ws, size_t ws_size,
                              hipStream_t stream) {
  const float* x  = (const float*)d_in[0];
  const float* Wq = (const float*)d_in[1];
  const float* Wk = (const float*)d_in[2];
  const float* Wv = (const float*)d_in[3];
  const float* Wo = (const float*)d_in[4];
  float* out = (float*)d_out;

  const size_t NX = (size_t)M_ * D_;
  const size_t NW = (size_t)D_ * D_;
  const size_t need = (4 * NX + 4 * NW) * sizeof(unsigned short);
  if (ws_size < need) return;

  unsigned short* ws  = (unsigned short*)d_ws;
  unsigned short* xb  = ws;
  unsigned short* wqb = xb + NX;   // wqb/wkb/wvb contiguous = stacked QKV weight
  unsigned short* wkb = wqb + NW;
  unsigned short* wvb = wkb + NW;
  unsigned short* wob = wvb + NW;
  unsigned short* Qb  = wob + NW;  // Qb/Kb/Vtb contiguous = fused-QKV output
  unsigned short* Yb  = xb;        // alias: x dead after QKV projections

  cvt_bf16<<<(int)(NX / 1024), 256, 0, stream>>>(x, xb, (int)NX);
  cvt_w4<<<4096, 256, 0, stream>>>(Wq, Wk, Wv, Wo, wqb, wkb, wvb, wob);

  // fused QKV projection: C[8192, 3072] = x @ [Wq;Wk;Wv]^T
  gemm_bt<3><<<(M_ / 128) * (3072 / 128), 256, 0, stream>>>(xb, wqb, Qb, M_, 3072, D_);

  attn<<<B_ * H_ * (T_ / 128), 256, 0, stream>>>(Qb, Qb + NX, Qb + 2 * NX, Yb);

  gemm_bt<1><<<(M_ / 128) * (D_ / 128), 256, 0, stream>>>(Yb, wob, out, M_, D_, D_);
}

// Round 13
// 167.191 us; speedup vs baseline: 3.1970x; 1.0508x over previous
//
#include <hip/hip_runtime.h>

typedef __attribute__((ext_vector_type(8))) short short8;
typedef __attribute__((ext_vector_type(4))) float f32x4;
typedef __attribute__((ext_vector_type(2))) unsigned int u32x2;

constexpr int B_ = 4, T_ = 2048, D_ = 1024, H_ = 16;
constexpr int M_ = B_ * T_;          // 8192 token rows
constexpr float SCL2 = 0.1803368801111f;  // (1/sqrt(64)) * log2(e)

#if __has_builtin(__builtin_amdgcn_exp2f)
#define EXP2F __builtin_amdgcn_exp2f
#else
#define EXP2F exp2f
#endif

#define DEV __device__ __forceinline__

DEV unsigned short f2bf(float f) {   // f32 -> bf16 RNE
  unsigned int u = __builtin_bit_cast(unsigned int, f);
  u += 0x7FFFu + ((u >> 16) & 1u);
  return (unsigned short)(u >> 16);
}

DEV void gload16(const unsigned short* g, unsigned short* l) {
  __builtin_amdgcn_global_load_lds(
      (const __attribute__((address_space(1))) unsigned int*)g,
      (__attribute__((address_space(3))) unsigned int*)l, 16, 0, 0);
}

// ---------------- f32 -> bf16 conversion ----------------
__global__ __launch_bounds__(256) void cvt_bf16(const float* __restrict__ in,
                                                unsigned short* __restrict__ out,
                                                int n) {
  int i = (blockIdx.x * 256 + threadIdx.x) * 4;
  if (i >= n) return;
  float4 f = *(const float4*)(in + i);
  ushort4 o;
  o.x = f2bf(f.x); o.y = f2bf(f.y); o.z = f2bf(f.z); o.w = f2bf(f.w);
  *(ushort4*)(out + i) = o;
}

// 4 weights in one launch (1024 blocks each)
__global__ __launch_bounds__(256) void cvt_w4(const float* __restrict__ w0, const float* __restrict__ w1,
                                              const float* __restrict__ w2, const float* __restrict__ w3,
                                              unsigned short* __restrict__ o0, unsigned short* __restrict__ o1,
                                              unsigned short* __restrict__ o2, unsigned short* __restrict__ o3) {
  int sel = blockIdx.x >> 10;
  const float* in = sel == 0 ? w0 : sel == 1 ? w1 : sel == 2 ? w2 : w3;
  unsigned short* out = sel == 0 ? o0 : sel == 1 ? o1 : sel == 2 ? o2 : o3;
  int i = ((blockIdx.x & 1023) * 256 + threadIdx.x) * 4;
  float4 f = *(const float4*)(in + i);
  ushort4 o;
  o.x = f2bf(f.x); o.y = f2bf(f.y); o.z = f2bf(f.z); o.w = f2bf(f.w);
  *(ushort4*)(out + i) = o;
}

// ---------------- GEMM: C[M,N] = A[M,K] * B[N,K]^T ----------------
// OUTMODE: 0 = bf16 row-major, 1 = f32 row-major,
//          3 = fused QKV: region by tn (0-7 Q, 8-15 K, 16-23 Vt-per-head)
// BK=64: 32 MFMA per barrier pair (2x amortization vs BK=32).
// T2 XOR-swizzle (slot ^= row&7, 8x16B slots/row): staged via pre-swizzled
// GLOBAL source (rule #21: gload_lds dest must stay linear), fragments read
// with matching XOR. Bank audit: lanes 0-7 cover 8 slot-groups -> 2-way (free).
template <int OUTMODE>
__global__ __launch_bounds__(256, 2) void gemm_bt(const unsigned short* __restrict__ A,
                                                  const unsigned short* __restrict__ B,
                                                  void* __restrict__ C,
                                                  int M, int N, int K) {
  constexpr int BM = 128, BN = 128, BK = 64;
  __shared__ __align__(16) unsigned short a_sh[2 * BM * BK];  // 32 KB
  __shared__ __align__(16) unsigned short b_sh[2 * BN * BK];  // 32 KB

  const int tid = threadIdx.x;
  const int lane = tid & 63;
  const int w = tid >> 6;
  const int l15 = lane & 15, lg = lane >> 4;
  const int wr = w >> 1, wc = w & 1;

  // XCD-chunked bijective swizzle: each XCD gets a contiguous run of tiles
  const int nwg = gridDim.x;
  const int swz = (blockIdx.x & 7) * (nwg >> 3) + (blockIdx.x >> 3);

  const int NT = N / BN;
  const int tm = swz / NT, tn = swz % NT;
  const unsigned short* Ab = A + (size_t)tm * BM * K;
  const unsigned short* Bb = B + (size_t)tn * BN * K;

  f32x4 acc[4][4];
#pragma unroll
  for (int m = 0; m < 4; ++m)
#pragma unroll
    for (int n = 0; n < 4; ++n) acc[m][n] = (f32x4){0.f, 0.f, 0.f, 0.f};

  // stage one BK=64 tile of A and B, source-swizzled: slot s of row r holds
  // global k8-group (s ^ (r&7)).
  auto stage = [&](int buf, int kt) {
    int k0 = kt * BK;
#pragma unroll
    for (int rnd = 0; rnd < 4; ++rnd) {
      int c = rnd * 256 + tid;            // 16B chunk id, 0..1023
      int row = c >> 3, s = c & 7;        // 8 chunks per 64-elem row
      int koff = k0 + 8 * (s ^ (row & 7));
      unsigned short* ldst_a = a_sh + buf * BM * BK + (rnd * 256 + w * 64) * 8;
      unsigned short* ldst_b = b_sh + buf * BN * BK + (rnd * 256 + w * 64) * 8;
      gload16(Ab + (size_t)row * K + koff, ldst_a);
      gload16(Bb + (size_t)row * K + koff, ldst_b);
    }
  };

  stage(0, 0);
  int cur = 0;
  const int NK = K / BK;                  // 16
  for (int kt = 0; kt < NK; ++kt) {
    __syncthreads();                      // drains vmcnt -> buf[cur] ready
    if (kt + 1 < NK) stage(cur ^ 1, kt + 1);
    const unsigned short* ab = a_sh + cur * BM * BK;
    const unsigned short* bb = b_sh + cur * BN * BK;
#pragma unroll
    for (int kk = 0; kk < 2; ++kk) {
      short8 af[4], bf8[4];
#pragma unroll
      for (int m = 0; m < 4; ++m) {
        int row = wr * 64 + m * 16 + l15;
        int slot = (kk * 4 + lg) ^ (row & 7);
        af[m] = *(const short8*)(ab + row * 64 + slot * 8);
      }
#pragma unroll
      for (int n = 0; n < 4; ++n) {
        int row = wc * 64 + n * 16 + l15;
        int slot = (kk * 4 + lg) ^ (row & 7);
        bf8[n] = *(const short8*)(bb + row * 64 + slot * 8);
      }
#pragma unroll
      for (int m = 0; m < 4; ++m)
#pragma unroll
        for (int n = 0; n < 4; ++n)
          acc[m][n] = __builtin_amdgcn_mfma_f32_16x16x32_bf16(af[m], bf8[n], acc[m][n], 0, 0, 0);
    }
    cur ^= 1;
  }

  const int row0 = tm * BM + wr * 64 + lg * 4;
  const int col0 = tn * BN + wc * 64 + l15;
#pragma unroll
  for (int m = 0; m < 4; ++m)
#pragma unroll
    for (int n = 0; n < 4; ++n) {
      if (OUTMODE == 3) {
        const int region = tn >> 3;               // 0=Q, 1=K, 2=V
        const int nc = col0 - (region << 10) + n * 16;
        const int mm = row0 + m * 16;
        if (region == 2) {
          // Vt-per-head: [(b*16+h)][d][s], r consecutive in s
          size_t base = (size_t)2 * 8388608 +
                        ((size_t)((mm >> 11) * 16 + (nc >> 6))) * 131072 +
                        (size_t)(nc & 63) * 2048 + (mm & 2047);
          ushort4 pk;
          pk.x = f2bf(acc[m][n][0]); pk.y = f2bf(acc[m][n][1]);
          pk.z = f2bf(acc[m][n][2]); pk.w = f2bf(acc[m][n][3]);
          *(ushort4*)((unsigned short*)C + base) = pk;
        } else {
          unsigned short* dst = (unsigned short*)C + (size_t)region * 8388608;
#pragma unroll
          for (int r = 0; r < 4; ++r)
            dst[(size_t)(mm + r) * 1024 + nc] = f2bf(acc[m][n][r]);
        }
      } else {
#pragma unroll
        for (int r = 0; r < 4; ++r) {
          size_t idx = (size_t)(row0 + m * 16 + r) * N + (col0 + n * 16);
          if (OUTMODE == 1)
            ((float*)C)[idx] = acc[m][n][r];
          else
            ((unsigned short*)C)[idx] = f2bf(acc[m][n][r]);
        }
      }
    }
}

// ---------------- causal flash attention (swapped-QK, KB=64, QB=128) --------
// Round-10 structure (round-7 + T13 defer-max) — unchanged this round.
__global__ __launch_bounds__(256, 3) void attn(const unsigned short* __restrict__ Q,
                                               const unsigned short* __restrict__ K,
                                               const unsigned short* __restrict__ Vt,
                                               unsigned short* __restrict__ Y) {
  __shared__ __align__(16) unsigned short k_sh[2][64 * 64];
  __shared__ __align__(16) unsigned short v_sh[2][64 * 64];   // [d][s], swizzled
  __shared__ __align__(16) unsigned short p_sh[4][32][72];    // per-wave P

  const int tid = threadIdx.x;
  const int lane = tid & 63;
  const int w = tid >> 6;
  const int l15 = lane & 15, lg = lane >> 4;

  const int bid = blockIdx.x;
  const int qt_blk = 15 - (bid >> 6);          // all heavy blocks dispatch first
  const int bh = bid & 63;
  const int h = bh & 15;
  const int b = bh >> 4;
  const int q0 = qt_blk * 128;
  const int qq0 = q0 + 32 * w;                 // this wave's first q-row

  const unsigned short* Qp = Q + ((size_t)(b * T_ + q0)) * D_ + h * 64;
  const unsigned short* Kp = K + ((size_t)(b * T_)) * D_ + h * 64;
  const unsigned short* Vtp = Vt + (size_t)bh * 131072;   // [64 d][2048 s]

  auto stK = [&](int buf, int kv0) {
#pragma unroll
    for (int j = 0; j < 2; ++j) {
      int c = j * 256 + tid;
      int row = c >> 3;
      gload16(Kp + (size_t)(kv0 + row) * D_ + 8 * ((c & 7) ^ (row & 7)),
              &k_sh[buf][(j * 256 + w * 64) * 8]);
    }
  };
  auto stV = [&](int buf, int kv0) {
#pragma unroll
    for (int j = 0; j < 2; ++j) {
      int c = j * 256 + tid;
      int d = c >> 3;
      gload16(Vtp + (size_t)d * 2048 + kv0 + 8 * ((c & 7) ^ (d & 7)),
              &v_sh[buf][(j * 256 + w * 64) * 8]);
    }
  };

  // Q fragments direct global -> registers (B-frag: row = q, k-contig)
  short8 qf[2][2];
#pragma unroll
  for (int qt = 0; qt < 2; ++qt)
#pragma unroll
    for (int kk = 0; kk < 2; ++kk)
      qf[qt][kk] = *(const short8*)(Qp + (size_t)(32 * w + 16 * qt + l15) * D_ + 32 * kk + 8 * lg);

  stK(0, 0);
  stV(0, 0);
  __syncthreads();

  unsigned short* p_w = &p_sh[w][0][0];

  const float NEGINF = -__builtin_inff();
  float ml[2] = {NEGINF, NEGINF};
  float ll[2] = {0.f, 0.f};
  f32x4 o[2][4];
#pragma unroll
  for (int qt = 0; qt < 2; ++qt)
#pragma unroll
    for (int t = 0; t < 4; ++t) o[qt][t] = (f32x4){0.f, 0.f, 0.f, 0.f};

  const int NI = 2 * qt_blk + 2;
  int cur = 0;
  for (int i = 0; i < NI; ++i) {
    const int kv0 = i * 64;
    if (i + 1 < NI) { stK(cur ^ 1, kv0 + 64); stV(cur ^ 1, kv0 + 64); }

    const bool active = (kv0 <= qq0 + 31);
    if (active) {
      // ---- S^T = K * Q^T  (16 MFMA) ----
      f32x4 sacc[2][4];
#pragma unroll
      for (int qt = 0; qt < 2; ++qt)
#pragma unroll
        for (int t = 0; t < 4; ++t) sacc[qt][t] = (f32x4){0.f, 0.f, 0.f, 0.f};
      const char* kb = (const char*)k_sh[cur];
      __builtin_amdgcn_s_setprio(1);
#pragma unroll
      for (int t = 0; t < 4; ++t) {
        int sr = 16 * t + l15;
        int sw = (sr & 7) << 4;
        short8 kf0 = *(const short8*)(kb + sr * 128 + ((16 * lg) ^ sw));
        short8 kf1 = *(const short8*)(kb + sr * 128 + ((64 + 16 * lg) ^ sw));
#pragma unroll
        for (int qt = 0; qt < 2; ++qt) {
          sacc[qt][t] = __builtin_amdgcn_mfma_f32_16x16x32_bf16(kf0, qf[qt][0], sacc[qt][t], 0, 0, 0);
          sacc[qt][t] = __builtin_amdgcn_mfma_f32_16x16x32_bf16(kf1, qf[qt][1], sacc[qt][t], 0, 0, 0);
        }
      }
      __builtin_amdgcn_s_setprio(0);

      // ---- online softmax per q-tile (in-register, T13 defer-max) ----
      float corr[2];
      bool defer[2];
#pragma unroll
      for (int qt = 0; qt < 2; ++qt) {
        const bool nomask = (kv0 + 63) <= (qq0 + 16 * qt);   // wave-uniform
        float sv[16];
        if (nomask) {
#pragma unroll
          for (int t = 0; t < 4; ++t)
#pragma unroll
            for (int r = 0; r < 4; ++r) sv[4 * t + r] = sacc[qt][t][r];
        } else {
          const int qg = qq0 + 16 * qt + l15;
#pragma unroll
          for (int t = 0; t < 4; ++t)
#pragma unroll
            for (int r = 0; r < 4; ++r) {
              int sg = kv0 + 16 * t + 4 * lg + r;
              sv[4 * t + r] = (sg <= qg) ? sacc[qt][t][r] : NEGINF;
            }
        }
        float a8[8], a4[4], a2[2];
#pragma unroll
        for (int k = 0; k < 8; ++k) a8[k] = fmaxf(sv[k], sv[k + 8]);
#pragma unroll
        for (int k = 0; k < 4; ++k) a4[k] = fmaxf(a8[k], a8[k + 4]);
        a2[0] = fmaxf(a4[0], a4[2]); a2[1] = fmaxf(a4[1], a4[3]);
        float mx = fmaxf(a2[0], a2[1]);
        mx = fmaxf(mx, __shfl_xor(mx, 16));
        mx = fmaxf(mx, __shfl_xor(mx, 32));
        // T13: keep old max when growth small (P bounded by 2^(8*SCL2) ~ 2.7)
        defer[qt] = (__all(mx <= ml[qt] + 8.0f) != 0);
        float mnew = defer[qt] ? ml[qt] : fmaxf(ml[qt], mx);
        corr[qt] = defer[qt] ? 1.0f : EXP2F((ml[qt] - mnew) * SCL2);
        float nms2 = mnew * SCL2;
        float pv[16];
#pragma unroll
        for (int k = 0; k < 16; ++k) pv[k] = EXP2F(fmaf(sv[k], SCL2, -nms2));
        float s8[8], s4[4], s2[2];
#pragma unroll
        for (int k = 0; k < 8; ++k) s8[k] = pv[k] + pv[k + 8];
#pragma unroll
        for (int k = 0; k < 4; ++k) s4[k] = s8[k] + s8[k + 4];
        s2[0] = s4[0] + s4[2]; s2[1] = s4[1] + s4[3];
        float ps = s2[0] + s2[1];
        ps += __shfl_xor(ps, 16);
        ps += __shfl_xor(ps, 32);
        ll[qt] = ll[qt] * corr[qt] + ps;
        ml[qt] = mnew;
        // pack P -> LDS via v_cvt_pk_bf16_f32 (RNE, lo=src0)
#pragma unroll
        for (int t = 0; t < 4; ++t) {
          unsigned lo, hi;
          asm("v_cvt_pk_bf16_f32 %0, %1, %2" : "=v"(lo) : "v"(pv[4 * t]), "v"(pv[4 * t + 1]));
          asm("v_cvt_pk_bf16_f32 %0, %1, %2" : "=v"(hi) : "v"(pv[4 * t + 2]), "v"(pv[4 * t + 3]));
          u32x2 pk = {lo, hi};
          *(u32x2*)(void*)(p_w + (16 * qt + l15) * 72 + 16 * t + 4 * lg) = pk;
        }
      }
      asm volatile("" ::: "memory");  // order P stores before P frag loads

      // ---- rescale O (skipped when deferred) ----
#pragma unroll
      for (int qt = 0; qt < 2; ++qt)
        if (!defer[qt]) {
#pragma unroll
          for (int r = 0; r < 4; ++r) {
            float cr = __shfl(corr[qt], 4 * lg + r);
#pragma unroll
            for (int t = 0; t < 4; ++t) o[qt][t][r] *= cr;
          }
        }

      // ---- O += P * V  (16 MFMA) ----
      short8 pa[2][2];
#pragma unroll
      for (int qt = 0; qt < 2; ++qt)
#pragma unroll
        for (int kk = 0; kk < 2; ++kk)
          pa[qt][kk] = *(const short8*)(p_w + (16 * qt + l15) * 72 + kk * 32 + 8 * lg);

      const char* vbT = (const char*)v_sh[cur];
      __builtin_amdgcn_s_setprio(1);
#pragma unroll
      for (int t = 0; t < 4; ++t) {
        int dr = 16 * t + l15;
        int sw = (dr & 7) << 4;
        short8 vf0 = *(const short8*)(vbT + dr * 128 + ((16 * lg) ^ sw));
        short8 vf1 = *(const short8*)(vbT + dr * 128 + ((64 + 16 * lg) ^ sw));
#pragma unroll
        for (int qt = 0; qt < 2; ++qt) {
          o[qt][t] = __builtin_amdgcn_mfma_f32_16x16x32_bf16(pa[qt][0], vf0, o[qt][t], 0, 0, 0);
          o[qt][t] = __builtin_amdgcn_mfma_f32_16x16x32_bf16(pa[qt][1], vf1, o[qt][t], 0, 0, 0);
        }
      }
      __builtin_amdgcn_s_setprio(0);
    }
    __syncthreads();
    cur ^= 1;
  }

  // ---- epilogue: Y[b, q, h*64 + d] = O / l ----
#pragma unroll
  for (int qt = 0; qt < 2; ++qt) {
    float linv = 1.0f / ll[qt];
#pragma unroll
    for (int r = 0; r < 4; ++r) {
      float li = __shfl(linv, 4 * lg + r);
      int qg = qq0 + 16 * qt + 4 * lg + r;
      unsigned short* Yp = Y + ((size_t)(b * T_ + qg)) * D_ + h * 64;
#pragma unroll
      for (int t = 0; t < 4; ++t)
        Yp[16 * t + l15] = f2bf(o[qt][t][r] * li);
    }
  }
}

// ---------------- launch ----------------
extern "C" void kernel_launch(void* const* d_in, const int* in_sizes, int n_in,
                              void* d_out, int out_size, void* d_ws, size_t ws_size,
                              hipStream_t stream) {
  const float* x  = (const float*)d_in[0];
  const float* Wq = (const float*)d_in[1];
  const float* Wk = (const float*)d_in[2];
  const float* Wv = (const float*)d_in[3];
  const float* Wo = (const float*)d_in[4];
  float* out = (float*)d_out;

  const size_t NX = (size_t)M_ * D_;
  const size_t NW = (size_t)D_ * D_;
  const size_t need = (4 * NX + 4 * NW) * sizeof(unsigned short);
  if (ws_size < need) return;

  unsigned short* ws  = (unsigned short*)d_ws;
  unsigned short* xb  = ws;
  unsigned short* wqb = xb + NX;   // wqb/wkb/wvb contiguous = stacked QKV weight
  unsigned short* wkb = wqb + NW;
  unsigned short* wvb = wkb + NW;
  unsigned short* wob = wvb + NW;
  unsigned short* Qb  = wob + NW;  // Qb/Kb/Vtb contiguous = fused-QKV output
  unsigned short* Yb  = xb;        // alias: x dead after QKV projections

  cvt_bf16<<<(int)(NX / 1024), 256, 0, stream>>>(x, xb, (int)NX);
  cvt_w4<<<4096, 256, 0, stream>>>(Wq, Wk, Wv, Wo, wqb, wkb, wvb, wob);

  // fused QKV projection: C[8192, 3072] = x @ [Wq;Wk;Wv]^T
  gemm_bt<3><<<(M_ / 128) * (3072 / 128), 256, 0, stream>>>(xb, wqb, Qb, M_, 3072, D_);

  attn<<<B_ * H_ * (T_ / 128), 256, 0, stream>>>(Qb, Qb + NX, Qb + 2 * NX, Yb);

  gemm_bt<1><<<(M_ / 128) * (D_ / 128), 256, 0, stream>>>(Yb, wob, out, M_, D_, D_);
}